// Round 2
// baseline (4552.523 us; speedup 1.0000x reference)
//
#include <hip/hip_runtime.h>

#define BB 16
#define NN 1024
#define TS 64
#define KS 16
#define PAD 68   // LDS row padding (floats): keeps float4 alignment, breaks bank patterns

typedef float4 f4;

__device__ __forceinline__ float wave_sum(float v) {
    #pragma unroll
    for (int m = 32; m >= 1; m >>= 1) v += __shfl_xor(v, m);
    return v;
}

// ---------------- squared norms: sq[b,n] = sum_c X[b,n,c]^2 ----------------
__global__ void sqnorm_kernel(const float* __restrict__ X, int C, float* __restrict__ sq) {
    int wave = threadIdx.x >> 6, lane = threadIdx.x & 63;
    int row = blockIdx.x * 4 + wave;           // [0, BB*NN)
    const float* Xr = X + (size_t)row * C;
    float s = 0.f;
    for (int c = lane; c < C; c += 64) { float v = Xr[c]; s += v * v; }
    s = wave_sum(s);
    if (lane == 0) sq[row] = s;
}

// ---------------- adjacency: W[b,i,j] = exp(2*pi.pj - |pi|^2 - |pj|^2) ----------------
__global__ __launch_bounds__(256)
void adj_kernel(const float* __restrict__ P, int C, const float* __restrict__ sq,
                float* __restrict__ W) {
    int b = blockIdx.z;
    int i0 = blockIdx.x * TS, j0 = blockIdx.y * TS;
    __shared__ float Pa[KS][PAD];
    __shared__ float Pb[KS][PAD];
    int tid = threadIdx.x, tx = tid & 15, ty = tid >> 4;
    float acc[4][4] = {};
    const float* Pbase = P + (size_t)b * NN * C;
    for (int c0 = 0; c0 < C; c0 += KS) {
        int i = tid >> 2, cq = (tid & 3) * 4;
        if (c0 + KS <= C) {
            f4 va = *(const f4*)&Pbase[(size_t)(i0 + i) * C + c0 + cq];
            f4 vb = *(const f4*)&Pbase[(size_t)(j0 + i) * C + c0 + cq];
            const float* ap = (const float*)&va; const float* bp = (const float*)&vb;
            #pragma unroll
            for (int q = 0; q < 4; q++) { Pa[cq + q][i] = ap[q]; Pb[cq + q][i] = bp[q]; }
        } else {
            #pragma unroll
            for (int q = 0; q < 4; q++) {
                int c = c0 + cq + q;
                Pa[cq + q][i] = (c < C) ? Pbase[(size_t)(i0 + i) * C + c] : 0.f;
                Pb[cq + q][i] = (c < C) ? Pbase[(size_t)(j0 + i) * C + c] : 0.f;
            }
        }
        __syncthreads();
        #pragma unroll
        for (int kk = 0; kk < KS; kk++) {
            f4 av = *(const f4*)&Pa[kk][ty * 4];
            f4 bv = *(const f4*)&Pb[kk][tx * 4];
            const float* ap = (const float*)&av; const float* bp = (const float*)&bv;
            #pragma unroll
            for (int p = 0; p < 4; p++)
                #pragma unroll
                for (int q = 0; q < 4; q++) acc[p][q] += ap[p] * bp[q];
        }
        __syncthreads();
    }
    const float* sqb = sq + b * NN;
    float* Wb = W + (size_t)b * NN * NN;
    #pragma unroll
    for (int p = 0; p < 4; p++) {
        int i = i0 + ty * 4 + p;
        float si = sqb[i];
        #pragma unroll
        for (int q = 0; q < 4; q++) {
            int j = j0 + tx * 4 + q;
            Wb[(size_t)i * NN + j] = __expf(2.f * acc[p][q] - si - sqb[j]);
        }
    }
}

// ---------------- row sums: full (incl diag) and off-diag-only (exact, by index) ----------------
__global__ void rowsum_kernel(const float* __restrict__ W, float* __restrict__ dsum,
                              float* __restrict__ dsumP) {
    int wave = threadIdx.x >> 6, lane = threadIdx.x & 63;
    int row = blockIdx.x * 4 + wave;           // [0, BB*NN)
    int i = row & (NN - 1);
    const f4* Wr = (const f4*)(W + (size_t)row * NN);
    float part = 0.f, diag = 0.f;
    #pragma unroll
    for (int it = 0; it < 4; it++) {
        int idx = it * 64 + lane;
        f4 v = Wr[idx];
        float* vp = (float*)&v;
        int dq = i - idx * 4;
        if (dq >= 0 && dq < 4) { diag += vp[dq]; vp[dq] = 0.f; }
        part += vp[0] + vp[1] + vp[2] + vp[3];
    }
    part = wave_sum(part);
    diag = wave_sum(diag);
    if (lane == 0) { dsumP[row] = part; dsum[row] = part + diag; }
}

// ---------------- per-row coefficients ----------------
__global__ void prep_kernel(const float* __restrict__ dsum, const float* __restrict__ dsumP,
                            float* dinv, float* dinvP, float* cA1, float* cA2,
                            float* cAV, float* cOne, float* cNeg1) {
    int i = blockIdx.x * 256 + threadIdx.x;
    float dv = rsqrtf(dsum[i]);
    float dp = rsqrtf(dsumP[i]);
    dinv[i] = dv; dinvP[i] = dp;
    cA1[i] = -dv; cA2[i] = -2.f * dv;
    cAV[i] = -dp; cOne[i] = 1.f; cNeg1[i] = -1.f;
}

// ---------------- layer-1 Z0 copy with pad 6->8 (zeros in pads) ----------------
__global__ void copyz0_kernel(const float* __restrict__ X, float* __restrict__ Z) {
    int idx = blockIdx.x * 256 + threadIdx.x;    // over BB*NN*8
    int bn = idx >> 3, c = idx & 7;
    Z[(size_t)bn * 48 + c] = (c < 6) ? X[bn * 6 + c] : 0.f;
}

// ---- dst[b,i,c] = cA[b,i] * sum_j W[b,i,j]*sIn[b,j]*Zin[b,j,c]  (+ cB[b,i]*prev[b,i,c]) ----
template<bool HAS_PREV, bool SKIP_DIAG>
__global__ __launch_bounds__(256)
void wgemm_kernel(const float* __restrict__ W, const float* __restrict__ sIn,
                  const float* __restrict__ Zin, int zStride,
                  const float* __restrict__ cA, const float* __restrict__ cB,
                  const float* __restrict__ prev, int pStride,
                  float* __restrict__ dst, int dStride, int Cpad) {
    int b = blockIdx.z;
    int i0 = blockIdx.x * TS, c0 = blockIdx.y * TS;
    __shared__ float As[KS][PAD];
    __shared__ float Bs[KS][PAD];
    int tid = threadIdx.x, tx = tid & 15, ty = tid >> 4;
    float acc[4][4] = {};
    const float* Wb = W + (size_t)b * NN * NN;
    const float* Zb = Zin + (size_t)b * NN * zStride;
    const float* sb = sIn + b * NN;
    for (int k0 = 0; k0 < NN; k0 += KS) {
        {   // A tile: W[i0+i][k0+k], transposed into As[k][i]
            int i = tid >> 2, kq = (tid & 3) * 4;
            f4 v = *(const f4*)&Wb[(size_t)(i0 + i) * NN + k0 + kq];
            float* vp = (float*)&v;
            if (SKIP_DIAG) {
                int gi = i0 + i;
                #pragma unroll
                for (int q = 0; q < 4; q++) if (gi == k0 + kq + q) vp[q] = 0.f;
            }
            #pragma unroll
            for (int q = 0; q < 4; q++) As[kq + q][i] = vp[q];
        }
        {   // B tile: Zin[k0+k][c0+c] * sIn[k0+k]
            int k = tid >> 4, c4 = (tid & 15) * 4;
            float s = sb[k0 + k];
            int col = c0 + c4;
            f4 v = make_float4(0.f, 0.f, 0.f, 0.f);
            if (col + 4 <= Cpad) v = *(const f4*)&Zb[(size_t)(k0 + k) * zStride + col];
            *(f4*)&Bs[k][c4] = make_float4(v.x * s, v.y * s, v.z * s, v.w * s);
        }
        __syncthreads();
        #pragma unroll
        for (int kk = 0; kk < KS; kk++) {
            f4 av = *(const f4*)&As[kk][ty * 4];
            f4 bv = *(const f4*)&Bs[kk][tx * 4];
            const float* ap = (const float*)&av; const float* bp = (const float*)&bv;
            #pragma unroll
            for (int p = 0; p < 4; p++)
                #pragma unroll
                for (int q = 0; q < 4; q++) acc[p][q] += ap[p] * bp[q];
        }
        __syncthreads();
    }
    const float* cAb = cA + b * NN;
    const float* cBb = cB + b * NN;
    #pragma unroll
    for (int p = 0; p < 4; p++) {
        int i = i0 + ty * 4 + p;
        float ca = cAb[i];
        float cb = HAS_PREV ? cBb[i] : 0.f;
        #pragma unroll
        for (int q = 0; q < 4; q++) {
            int c = c0 + tx * 4 + q;
            if (c < Cpad) {
                float v = ca * acc[p][q];
                if (HAS_PREV) v += cb * prev[((size_t)b * NN + i) * pStride + c];
                dst[((size_t)b * NN + i) * dStride + c] = v;
            }
        }
    }
}

// -------- feature GEMM: out = relu(A @ Wk + bias), A = [slice0 | slices 1..K-1] --------
// k-index kk in [0, Kp): kk<Cpad reads A0 (slice 0), else Ar at kk-Cpad.
// Weight row for kk: (kk>>shift)*Cin + (kk & (Cpad-1)), zero if pad lane.
__global__ __launch_bounds__(256)
void fgemm_kernel(const float* __restrict__ A0, int s0,
                  const float* __restrict__ Ar, int sr,
                  int Kp, int Cpad, int shift, int Cin,
                  const float* __restrict__ Wt, const float* __restrict__ bias,
                  float* __restrict__ out, int Cout) {
    int m0 = blockIdx.x * TS, c0 = blockIdx.y * TS;
    __shared__ float As[KS][PAD];
    __shared__ float Bs[KS][PAD];
    int tid = threadIdx.x, tx = tid & 15, ty = tid >> 4;
    float acc[4][4] = {};
    for (int k0 = 0; k0 < Kp; k0 += KS) {
        {   // A tile (4-float groups never straddle the Cpad boundary: Cpad % 4 == 0)
            int i = tid >> 2, kq = (tid & 3) * 4;
            int kk = k0 + kq;
            const float* src = (kk < Cpad) ? &A0[(size_t)(m0 + i) * s0 + kk]
                                           : &Ar[(size_t)(m0 + i) * sr + (kk - Cpad)];
            f4 v = *(const f4*)src;
            const float* vp = (const float*)&v;
            #pragma unroll
            for (int q = 0; q < 4; q++) As[kq + q][i] = vp[q];
        }
        {   // B tile: weight rows, zero for pad lanes
            int k = tid >> 4, c4 = (tid & 15) * 4;
            int kk = k0 + k;
            int c = kk & (Cpad - 1);
            f4 v = make_float4(0.f, 0.f, 0.f, 0.f);
            if (c < Cin) {
                int wrow = (kk >> shift) * Cin + c;
                v = *(const f4*)&Wt[(size_t)wrow * Cout + c0 + c4];
            }
            *(f4*)&Bs[k][c4] = v;
        }
        __syncthreads();
        #pragma unroll
        for (int kk = 0; kk < KS; kk++) {
            f4 av = *(const f4*)&As[kk][ty * 4];
            f4 bv = *(const f4*)&Bs[kk][tx * 4];
            const float* ap = (const float*)&av; const float* bp = (const float*)&bv;
            #pragma unroll
            for (int p = 0; p < 4; p++)
                #pragma unroll
                for (int q = 0; q < 4; q++) acc[p][q] += ap[p] * bp[q];
        }
        __syncthreads();
    }
    #pragma unroll
    for (int p = 0; p < 4; p++) {
        int m = m0 + ty * 4 + p;
        #pragma unroll
        for (int q = 0; q < 4; q++) {
            int c = c0 + tx * 4 + q;
            float v = acc[p][q] + bias[c];
            out[(size_t)m * Cout + c] = v > 0.f ? v : 0.f;
        }
    }
}

// ---------------- M partials: part[z][i][j] = sum_{k in chunk} X[k,i]*V[k,j] ----------------
__global__ __launch_bounds__(256)
void mgemm_kernel(const float* __restrict__ X, const float* __restrict__ V,
                  float* __restrict__ part, int Cout, int kChunk) {
    int i0 = blockIdx.x * TS, j0 = blockIdx.y * TS;
    int kStart = blockIdx.z * kChunk;
    __shared__ float As[KS][PAD];
    __shared__ float Bs[KS][PAD];
    int tid = threadIdx.x, tx = tid & 15, ty = tid >> 4;
    float acc[4][4] = {};
    for (int k0 = kStart; k0 < kStart + kChunk; k0 += KS) {
        int k = tid >> 4, c4 = (tid & 15) * 4;
        *(f4*)&As[k][c4] = *(const f4*)&X[(size_t)(k0 + k) * Cout + i0 + c4];
        *(f4*)&Bs[k][c4] = *(const f4*)&V[(size_t)(k0 + k) * Cout + j0 + c4];
        __syncthreads();
        #pragma unroll
        for (int kk = 0; kk < KS; kk++) {
            f4 av = *(const f4*)&As[kk][ty * 4];
            f4 bv = *(const f4*)&Bs[kk][tx * 4];
            const float* ap = (const float*)&av; const float* bp = (const float*)&bv;
            #pragma unroll
            for (int p = 0; p < 4; p++)
                #pragma unroll
                for (int q = 0; q < 4; q++) acc[p][q] += ap[p] * bp[q];
        }
        __syncthreads();
    }
    float* pt = part + (size_t)blockIdx.z * Cout * Cout;
    #pragma unroll
    for (int p = 0; p < 4; p++)
        #pragma unroll
        for (int q = 0; q < 4; q++)
            pt[(size_t)(i0 + ty * 4 + p) * Cout + j0 + tx * 4 + q] = acc[p][q];
}

// ---------------- Frobenius norm of summed split-K partials (deterministic) ----------------
__global__ void fro1_kernel(const float* __restrict__ part, int nElem, int splitk,
                            float* __restrict__ blockSS) {
    int tid = threadIdx.x;
    float ss = 0.f;
    for (int idx = blockIdx.x * 256 + tid; idx < nElem; idx += 1024 * 256) {
        float s = 0.f;
        for (int z = 0; z < splitk; z++) s += part[(size_t)z * nElem + idx];
        ss += s * s;
    }
    __shared__ float red[256];
    red[tid] = ss; __syncthreads();
    for (int m = 128; m >= 1; m >>= 1) { if (tid < m) red[tid] += red[tid + m]; __syncthreads(); }
    if (tid == 0) blockSS[blockIdx.x] = red[0];
}

__global__ void fro2_kernel(const float* __restrict__ blockSS, float* __restrict__ outp) {
    int tid = threadIdx.x;
    float s = 0.f;
    for (int i = tid; i < 1024; i += 256) s += blockSS[i];
    __shared__ float red[256];
    red[tid] = s; __syncthreads();
    for (int m = 128; m >= 1; m >>= 1) { if (tid < m) red[tid] += red[tid + m]; __syncthreads(); }
    if (tid == 0) *outp = sqrtf(red[0]);
}

// ---------------- max-pool over points ----------------
__global__ void pool_kernel(const float* __restrict__ X, float* __restrict__ out) {
    int b = blockIdx.x;
    int c = blockIdx.y * 256 + threadIdx.x;
    const float* Xb = X + (size_t)b * NN * 1024 + c;
    float m = -1e30f;
    for (int n = 0; n < NN; n++) m = fmaxf(m, Xb[(size_t)n * 1024]);
    out[b * 1024 + c] = m;
}

// ---------------- small FC ----------------
__global__ void fc_kernel(const float* __restrict__ in, const float* __restrict__ Wt,
                          const float* __restrict__ bias, float* __restrict__ out,
                          int K, int O, int doRelu) {
    int b = blockIdx.x;
    int o = blockIdx.y * 64 + threadIdx.x;
    if (o >= O) return;
    float acc = bias[o];
    const float* ib = in + b * K;
    for (int k = 0; k < K; k++) acc += ib[k] * Wt[(size_t)k * O + o];
    if (doRelu) acc = fmaxf(acc, 0.f);
    out[b * O + o] = acc;
}

extern "C" void kernel_launch(void* const* d_in, const int* in_sizes, int n_in,
                              void* d_out, int out_size, void* d_ws, size_t ws_size,
                              hipStream_t stream) {
    const float* x   = (const float*)d_in[0];
    const float* w1  = (const float*)d_in[4];
    const float* b1  = (const float*)d_in[5];
    const float* w2  = (const float*)d_in[6];
    const float* b2  = (const float*)d_in[7];
    const float* w3  = (const float*)d_in[8];
    const float* b3  = (const float*)d_in[9];
    const float* fw1 = (const float*)d_in[10];
    const float* fb1 = (const float*)d_in[11];
    const float* fw2 = (const float*)d_in[12];
    const float* fb2 = (const float*)d_in[13];
    const float* fw3 = (const float*)d_in[14];
    const float* fb3 = (const float*)d_in[15];
    float* out = (float*)d_out;

    char* ws = (char*)d_ws;
    size_t off = 0;
    auto alloc = [&](size_t bytes) -> void* {
        void* p = ws + off; off += (bytes + 255) & ~(size_t)255; return p;
    };
    // Peak usage: 64 + 64 + 8 + 32 + 64 + ~1 MiB = ~233 MiB
    float* Wbuf  = (float*)alloc((size_t)BB * NN * NN * 4);      // 64 MiB; Mpart aliases after V-step
    float* Zbuf  = (float*)alloc((size_t)BB * NN * 1024 * 4);    // 64 MiB; Z slices 1..K-1, then V
    float* out1  = (float*)alloc((size_t)BB * NN * 128 * 4);     // 8 MiB
    float* out2  = (float*)alloc((size_t)BB * NN * 512 * 4);     // 32 MiB
    float* out3  = (float*)alloc((size_t)BB * NN * 1024 * 4);    // 64 MiB
    float* sq    = (float*)alloc(BB * NN * 4);
    float* dsum  = (float*)alloc(BB * NN * 4);
    float* dsumP = (float*)alloc(BB * NN * 4);
    float* dinv  = (float*)alloc(BB * NN * 4);
    float* dinvP = (float*)alloc(BB * NN * 4);
    float* cA1   = (float*)alloc(BB * NN * 4);
    float* cA2   = (float*)alloc(BB * NN * 4);
    float* cAV   = (float*)alloc(BB * NN * 4);
    float* cOne  = (float*)alloc(BB * NN * 4);
    float* cNeg1 = (float*)alloc(BB * NN * 4);
    float* pooled= (float*)alloc(BB * 1024 * 4);
    float* h1    = (float*)alloc(BB * 512 * 4);
    float* h2    = (float*)alloc(BB * 128 * 4);
    float* blockSS = (float*)alloc(1024 * 4);
    float* Mpart = Wbuf;   // W is dead once the V-step has run
    (void)ws_size; (void)in_sizes; (void)n_in; (void)out_size;

    struct Layer { const float* Xp; int C, Cpad, shift, K, Cout; const float* Wk; const float* bk;
                   float* outp; int rIdx, splitk; };
    Layer L[3] = {
        { x,    6,   8,   3, 6, 128,  w1, b1, out1, 160, 64 },
        { out1, 128, 128, 7, 5, 512,  w2, b2, out2, 161, 32 },
        { out2, 512, 512, 9, 3, 1024, w3, b3, out3, 162, 8  },
    };

    for (int l = 0; l < 3; l++) {
        const Layer& P = L[l];
        sqnorm_kernel<<<BB * NN / 4, 256, 0, stream>>>(P.Xp, P.C, sq);
        adj_kernel<<<dim3(NN / TS, NN / TS, BB), 256, 0, stream>>>(P.Xp, P.C, sq, Wbuf);
        rowsum_kernel<<<BB * NN / 4, 256, 0, stream>>>(Wbuf, dsum, dsumP);
        prep_kernel<<<BB * NN / 256, 256, 0, stream>>>(dsum, dsumP, dinv, dinvP, cA1, cA2, cAV, cOne, cNeg1);

        // Z-slice layout: layer 0 keeps slice 0 in Zbuf (padded 6->8, row width 48);
        // layers 1/2 use the previous layer's output directly as slice 0.
        const float* z0p; int z0s, zrs;
        if (l == 0) {
            copyz0_kernel<<<BB * NN * 8 / 256, 256, 0, stream>>>(x, Zbuf);
            z0p = Zbuf; z0s = P.K * P.Cpad; zrs = z0s;           // 48
        } else {
            z0p = P.Xp; z0s = P.Cpad; zrs = (P.K - 1) * P.Cpad;
        }
        auto slice = [&](int k) -> float* {   // k >= 1
            return (l == 0) ? Zbuf + k * P.Cpad : Zbuf + (size_t)(k - 1) * P.Cpad;
        };
        int cGrid = (P.Cpad + TS - 1) / TS;
        // Z1 = -dinv .* (W @ (dinv .* Z0))
        wgemm_kernel<false, false><<<dim3(NN / TS, cGrid, BB), 256, 0, stream>>>(
            Wbuf, dinv, z0p, z0s, cA1, cOne, (const float*)nullptr, 0,
            slice(1), zrs, P.Cpad);
        // Zk = -2*dinv .* (W @ (dinv .* Z_{k-1})) - Z_{k-2}
        for (int k = 2; k < P.K; k++) {
            const float* pv = (k == 2) ? z0p : slice(k - 2);
            int pvs = (k == 2) ? z0s : zrs;
            wgemm_kernel<true, false><<<dim3(NN / TS, cGrid, BB), 256, 0, stream>>>(
                Wbuf, dinv, slice(k - 1), zrs, cA2, cNeg1, pv, pvs,
                slice(k), zrs, P.Cpad);
        }
        // out = relu(concat_k(Z_k) @ Wk + b)
        fgemm_kernel<<<dim3(BB * NN / TS, P.Cout / TS), 256, 0, stream>>>(
            z0p, z0s, (l == 0) ? Zbuf + P.Cpad : Zbuf, zrs,
            P.K * P.Cpad, P.Cpad, P.shift, P.C, P.Wk, P.bk, P.outp, P.Cout);
        // V = out - dinvP .* (W_nodiag @ (dinvP .* out));  V aliases Zbuf (Z dead)
        wgemm_kernel<true, true><<<dim3(NN / TS, P.Cout / TS, BB), 256, 0, stream>>>(
            Wbuf, dinvP, P.outp, P.Cout, cAV, cOne, P.outp, P.Cout,
            Zbuf, P.Cout, P.Cout);
        // M = out^T V (split-K into Mpart, aliases Wbuf: W dead now)
        int kChunk = BB * NN / P.splitk;
        mgemm_kernel<<<dim3(P.Cout / TS, P.Cout / TS, P.splitk), 256, 0, stream>>>(
            P.outp, Zbuf, Mpart, P.Cout, kChunk);
        fro1_kernel<<<1024, 256, 0, stream>>>(Mpart, P.Cout * P.Cout, P.splitk, blockSS);
        fro2_kernel<<<1, 256, 0, stream>>>(blockSS, out + P.rIdx);
    }
    pool_kernel<<<dim3(BB, 1024 / 256), 256, 0, stream>>>(out3, pooled);
    fc_kernel<<<dim3(BB, 512 / 64), 64, 0, stream>>>(pooled, fw1, fb1, h1, 1024, 512, 1);
    fc_kernel<<<dim3(BB, 128 / 64), 64, 0, stream>>>(h1, fw2, fb2, h2, 512, 128, 1);
    fc_kernel<<<dim3(BB, 1), 64, 0, stream>>>(h2, fw3, fb3, out, 128, 10, 0);
}

// Round 3
// 1910.937 us; speedup vs baseline: 2.3824x; 2.3824x over previous
//
#include <hip/hip_runtime.h>

#define BB 16
#define NN 1024
#define LDT 16384          // column count of all transposed feature buffers

typedef float4 f4;
typedef __attribute__((ext_vector_type(8))) short bf16x8;
typedef __attribute__((ext_vector_type(4))) float f32x4;

// bf16 pack/unpack (RNE)
__device__ __forceinline__ unsigned f2b1(float f) {
    unsigned u = __builtin_bit_cast(unsigned, f);
    return (u + 0x7fffu + ((u >> 16) & 1u)) >> 16;
}
__device__ __forceinline__ float b2f1(unsigned s) {
    unsigned u = (s & 0xffffu) << 16;
    return __builtin_bit_cast(float, u);
}

// LDS tile element offset with XOR swizzle (tile is [row][k] = [128][64] shorts)
#define SW(r, k) ((r) * 64 + ((k) ^ (((r) & 7) << 3)))

__device__ __forceinline__ float wave_sum(float v) {
    #pragma unroll
    for (int m = 32; m >= 1; m >>= 1) v += __shfl_xor(v, m);
    return v;
}

// ---- shared MFMA inner step: one 64-deep k-tile, 4x4 16x16 frags per wave ----
__device__ __forceinline__ void mfma_step(const short* As, const short* Bs,
                                          f32x4 (&acc)[4][4], int wr, int wc, int lane) {
    int la = lane & 15;
    #pragma unroll
    for (int ks = 0; ks < 2; ks++) {
        int kb = ks * 32 + (lane >> 4) * 8;
        bf16x8 a[4], b[4];
        #pragma unroll
        for (int f = 0; f < 4; f++) {
            int row = wr * 64 + f * 16 + la;
            a[f] = *(const bf16x8*)&As[SW(row, kb)];
        }
        #pragma unroll
        for (int f = 0; f < 4; f++) {
            int col = wc * 64 + f * 16 + la;
            b[f] = *(const bf16x8*)&Bs[SW(col, kb)];
        }
        #pragma unroll
        for (int fr = 0; fr < 4; fr++)
            #pragma unroll
            for (int fc = 0; fc < 4; fc++)
                acc[fr][fc] = __builtin_amdgcn_mfma_f32_16x16x32_bf16(a[fr], b[fc], acc[fr][fc], 0, 0, 0);
    }
}

// ---- direct row-copy staging: T[r][k] = src[r*stride + col_base + k], 128x64 ----
__device__ __forceinline__ void stage_rows(short* T, const unsigned short* src,
                                           size_t row_stride, size_t col_base, int tid) {
    #pragma unroll
    for (int n = 0; n < 4; n++) {
        int q = n * 256 + tid;
        int r = q >> 3, k8 = (q & 7) * 8;
        uint4 v = *(const uint4*)&src[(size_t)r * row_stride + col_base + k8];
        *(uint4*)&T[SW(r, k8)] = v;
    }
}

// ---- transpose staging (pair-pack): T[r=0..127][c=0..63] = src[(c0+c)*LDT + col_base + r] ----
__device__ __forceinline__ void stage_tr(short* T, const unsigned short* src,
                                         size_t col_base, int c0, int Cvalid, int tid) {
    #pragma unroll
    for (int n = 0; n < 2; n++) {
        int q = n * 256 + tid;
        int p = q >> 4, h = q & 15;
        int cg = c0 + 2 * p;
        uint4 r0 = make_uint4(0, 0, 0, 0), r1 = make_uint4(0, 0, 0, 0);
        if (cg < Cvalid)     r0 = *(const uint4*)&src[(size_t)cg * LDT + col_base + 8 * h];
        if (cg + 1 < Cvalid) r1 = *(const uint4*)&src[(size_t)(cg + 1) * LDT + col_base + 8 * h];
        const unsigned* a0 = (const unsigned*)&r0;
        const unsigned* a1 = (const unsigned*)&r1;
        #pragma unroll
        for (int e = 0; e < 8; e++) {
            unsigned lo = (e & 1) ? (a0[e >> 1] >> 16) : (a0[e >> 1] & 0xffffu);
            unsigned hi = (e & 1) ? (a1[e >> 1] >> 16) : (a1[e >> 1] & 0xffffu);
            int r = 8 * h + e;
            *(unsigned*)&T[SW(r, 2 * p)] = lo | (hi << 16);
        }
    }
}

// ================= input prep =================
__global__ void xt_prep_kernel(const float* __restrict__ x, short* __restrict__ xh,
                               short* __restrict__ xl) {
    int m = blockIdx.x * 256 + threadIdx.x;
    #pragma unroll
    for (int c = 0; c < 8; c++) {
        float v = (c < 6) ? x[(size_t)m * 6 + c] : 0.f;
        unsigned h = f2b1(v);
        unsigned l = f2b1(v - b2f1(h));
        xh[(size_t)c * LDT + m] = (short)h;
        xl[(size_t)c * LDT + m] = (short)l;
    }
}

__global__ void wtt_prep_kernel(const float* __restrict__ Wk, short* __restrict__ WtT,
                                int Kp64, int KpValid, int CpadM1, int shift, int Cin, int Cout) {
    int idx = blockIdx.x * 256 + threadIdx.x;
    if (idx >= Cout * Kp64) return;
    int co = idx / Kp64, kk = idx - co * Kp64;
    int c = kk & CpadM1;
    float val = 0.f;
    if (kk < KpValid && c < Cin)
        val = Wk[((size_t)(kk >> shift) * Cin + c) * Cout + co];
    WtT[(size_t)co * Kp64 + kk] = (short)f2b1(val);
}

// ================= squared norms from hi/lo (partial over 128-c chunks) =================
__global__ void sqt_part_kernel(const short* __restrict__ H, const short* __restrict__ L,
                                int C, float* __restrict__ dst) {
    int m = blockIdx.x * 256 + threadIdx.x;
    int cb = blockIdx.y * 128;
    int ce = min(cb + 128, C);
    const unsigned short* Hp = (const unsigned short*)H;
    const unsigned short* Lp = (const unsigned short*)L;
    float s = 0.f;
    for (int c = cb; c < ce; c++) {
        float v = b2f1(Hp[(size_t)c * LDT + m]) + b2f1(Lp[(size_t)c * LDT + m]);
        s += v * v;
    }
    dst[(size_t)blockIdx.y * LDT + m] = s;
}
__global__ void sqt_red_kernel(const float* __restrict__ part, int NC, float* __restrict__ sq) {
    int m = blockIdx.x * 256 + threadIdx.x;
    float s = 0.f;
    for (int y = 0; y < NC; y++) s += part[(size_t)y * LDT + m];
    sq[m] = s;
}

// ================= adjacency: W[b][j][i] = exp(2G - sq_i - sq_j), hi/lo 3-term MFMA =================
__global__ __launch_bounds__(256)
void adj_mfma_kernel(const short* __restrict__ XTh, const short* __restrict__ XTl,
                     int ck64, int Cvalid, const float* __restrict__ sq,
                     short* __restrict__ Wb) {
    __shared__ short Ah[128 * 64], Al[128 * 64], Bh[128 * 64], Bl[128 * 64];
    int tid = threadIdx.x, lane = tid & 63, w = tid >> 6;
    int wr = w >> 1, wc = w & 1;
    int b = blockIdx.z, i0 = blockIdx.x * 128, j0 = blockIdx.y * 128;
    size_t bo = (size_t)b * NN;
    f32x4 acc[4][4] = {};
    const unsigned short* Hs = (const unsigned short*)XTh;
    const unsigned short* Ls = (const unsigned short*)XTl;
    for (int t = 0; t < ck64; t++) {
        int c0 = t * 64;
        stage_tr(Ah, Hs, bo + i0, c0, Cvalid, tid);
        stage_tr(Al, Ls, bo + i0, c0, Cvalid, tid);
        stage_tr(Bh, Hs, bo + j0, c0, Cvalid, tid);
        stage_tr(Bl, Ls, bo + j0, c0, Cvalid, tid);
        __syncthreads();
        int la = lane & 15;
        #pragma unroll
        for (int ks = 0; ks < 2; ks++) {
            int kb = ks * 32 + (lane >> 4) * 8;
            bf16x8 ah[4], al[4], bh[4], bl[4];
            #pragma unroll
            for (int f = 0; f < 4; f++) {
                int row = wr * 64 + f * 16 + la;
                ah[f] = *(const bf16x8*)&Ah[SW(row, kb)];
                al[f] = *(const bf16x8*)&Al[SW(row, kb)];
                int col = wc * 64 + f * 16 + la;
                bh[f] = *(const bf16x8*)&Bh[SW(col, kb)];
                bl[f] = *(const bf16x8*)&Bl[SW(col, kb)];
            }
            #pragma unroll
            for (int fr = 0; fr < 4; fr++)
                #pragma unroll
                for (int fc = 0; fc < 4; fc++) {
                    acc[fr][fc] = __builtin_amdgcn_mfma_f32_16x16x32_bf16(ah[fr], bh[fc], acc[fr][fc], 0, 0, 0);
                    acc[fr][fc] = __builtin_amdgcn_mfma_f32_16x16x32_bf16(ah[fr], bl[fc], acc[fr][fc], 0, 0, 0);
                    acc[fr][fc] = __builtin_amdgcn_mfma_f32_16x16x32_bf16(al[fr], bh[fc], acc[fr][fc], 0, 0, 0);
                }
        }
        __syncthreads();
    }
    const float* sqb = sq + bo;
    short* Wout = Wb + bo * NN;
    #pragma unroll
    for (int fr = 0; fr < 4; fr++) {
        int ib = i0 + wr * 64 + fr * 16 + (lane >> 4) * 4;
        f4 si = *(const f4*)&sqb[ib];
        const float* sip = (const float*)&si;
        #pragma unroll
        for (int fc = 0; fc < 4; fc++) {
            int jb = j0 + wc * 64 + fc * 16 + (lane & 15);
            float sj = sqb[jb];
            const float* av = (const float*)&acc[fr][fc];
            unsigned lo = f2b1(__expf(2.f * av[0] - sip[0] - sj)) |
                          (f2b1(__expf(2.f * av[1] - sip[1] - sj)) << 16);
            unsigned hi = f2b1(__expf(2.f * av[2] - sip[2] - sj)) |
                          (f2b1(__expf(2.f * av[3] - sip[3] - sj)) << 16);
            // symmetric trick: write row jb, cols ib..ib+3 (coalesced 8B)
            *(uint2*)&Wout[(size_t)jb * NN + ib] = make_uint2(lo, hi);
        }
    }
}

// ================= row sums (bf16 W, diag excluded by index, fp32 accum) =================
__global__ void rowsum_kernel(const short* __restrict__ W, float* __restrict__ dsum,
                              float* __restrict__ dsumP) {
    int wave = threadIdx.x >> 6, lane = threadIdx.x & 63;
    int row = blockIdx.x * 4 + wave;          // global b*NN+i
    int i = row & (NN - 1);
    const unsigned short* Wr = (const unsigned short*)W + (size_t)row * NN;
    float part = 0.f, diag = 0.f;
    #pragma unroll
    for (int it = 0; it < 2; it++) {
        int j8 = (it * 64 + lane) * 8;
        uint4 v = *(const uint4*)&Wr[j8];
        const unsigned* vp = (const unsigned*)&v;
        #pragma unroll
        for (int e = 0; e < 4; e++) {
            float lo = b2f1(vp[e]), hi = b2f1(vp[e] >> 16);
            if (j8 + 2 * e == i)     { diag += lo; lo = 0.f; }
            if (j8 + 2 * e + 1 == i) { diag += hi; hi = 0.f; }
            part += lo + hi;
        }
    }
    part = wave_sum(part);
    diag = wave_sum(diag);
    if (lane == 0) { dsumP[row] = part; dsum[row] = part + diag; }
}

__global__ void prep_kernel(const float* __restrict__ dsum, const float* __restrict__ dsumP,
                            float* dinv, float* dinvP, float* cA1, float* cA2,
                            float* cAV, float* cOne, float* cNeg1) {
    int i = blockIdx.x * 256 + threadIdx.x;
    float dv = rsqrtf(dsum[i]);
    float dp = rsqrtf(dsumP[i]);
    dinv[i] = dv; dinvP[i] = dp;
    cA1[i] = -dv; cA2[i] = -2.f * dv;
    cAV[i] = -dp; cOne[i] = 1.f; cNeg1[i] = -1.f;
}

// ========== W-GEMM: DstT[c][i] = cA_i * sum_j W[i][j]*sIn_j*ZinT[c][j] (+ cB_i*PrevT[c][i]) ==========
template<bool HAS_PREV, bool SKIP_DIAG>
__global__ __launch_bounds__(256)
void wgemm_mfma_kernel(const short* __restrict__ W, const float* __restrict__ sIn,
                       const short* __restrict__ ZinT,
                       const float* __restrict__ cA, const float* __restrict__ cB,
                       const short* __restrict__ PrevT, short* __restrict__ DstT,
                       int Cvalid) {
    __shared__ short As[128 * 64], Bs[128 * 64];
    int tid = threadIdx.x, lane = tid & 63, w = tid >> 6;
    int wr = w >> 1, wc = w & 1;
    int b = blockIdx.z, i0 = blockIdx.x * 128, c0t = blockIdx.y * 128;
    size_t bo = (size_t)b * NN;
    const unsigned short* Wp = (const unsigned short*)W + bo * NN;
    const unsigned short* Zp = (const unsigned short*)ZinT;
    f32x4 acc[4][4] = {};
    for (int k0 = 0; k0 < NN; k0 += 64) {
        // A: W rows i0..i0+127, cols k0..k0+63 (optional diag zero)
        #pragma unroll
        for (int n = 0; n < 4; n++) {
            int q = n * 256 + tid;
            int r = q >> 3, k8 = (q & 7) * 8;
            uint4 v = *(const uint4*)&Wp[(size_t)(i0 + r) * NN + k0 + k8];
            if (SKIP_DIAG) {
                int d = (i0 + r) - (k0 + k8);
                if ((unsigned)d < 8u) {
                    unsigned* vp = (unsigned*)&v;
                    vp[d >> 1] &= (d & 1) ? 0x0000ffffu : 0xffff0000u;
                }
            }
            *(uint4*)&As[SW(r, k8)] = v;
        }
        // B: ZinT rows (channels), cols = points k0.. scaled by sIn
        #pragma unroll
        for (int n = 0; n < 4; n++) {
            int q = n * 256 + tid;
            int c = q >> 3, j8 = (q & 7) * 8;
            uint4 v = make_uint4(0, 0, 0, 0);
            if (c0t + c < Cvalid) {
                uint4 raw = *(const uint4*)&Zp[(size_t)(c0t + c) * LDT + bo + k0 + j8];
                f4 s0 = *(const f4*)&sIn[bo + k0 + j8];
                f4 s1 = *(const f4*)&sIn[bo + k0 + j8 + 4];
                const unsigned* rp = (const unsigned*)&raw;
                const float* sp0 = (const float*)&s0;
                const float* sp1 = (const float*)&s1;
                unsigned* vp = (unsigned*)&v;
                #pragma unroll
                for (int e = 0; e < 4; e++) {
                    float se0 = (e < 2) ? sp0[2 * e] : sp1[2 * e - 4];
                    float se1 = (e < 2) ? sp0[2 * e + 1] : sp1[2 * e - 3];
                    vp[e] = f2b1(b2f1(rp[e]) * se0) | (f2b1(b2f1(rp[e] >> 16) * se1) << 16);
                }
            }
            *(uint4*)&Bs[SW(c, j8)] = v;
        }
        __syncthreads();
        mfma_step(As, Bs, acc, wr, wc, lane);
        __syncthreads();
    }
    const float* cAb = cA + bo;
    const float* cBb = cB + bo;
    #pragma unroll
    for (int fr = 0; fr < 4; fr++) {
        int ib = i0 + wr * 64 + fr * 16 + (lane >> 4) * 4;
        f4 ca = *(const f4*)&cAb[ib];
        const float* cap = (const float*)&ca;
        f4 cb;
        const float* cbp = (const float*)&cb;
        if (HAS_PREV) cb = *(const f4*)&cBb[ib];
        #pragma unroll
        for (int fc = 0; fc < 4; fc++) {
            int c = c0t + wc * 64 + fc * 16 + (lane & 15);
            if (c < Cvalid) {
                const float* av = (const float*)&acc[fr][fc];
                float o[4];
                if (HAS_PREV) {
                    uint2 pv = *(const uint2*)&PrevT[(size_t)c * LDT + bo + ib];
                    o[0] = cap[0] * av[0] + cbp[0] * b2f1(pv.x);
                    o[1] = cap[1] * av[1] + cbp[1] * b2f1(pv.x >> 16);
                    o[2] = cap[2] * av[2] + cbp[2] * b2f1(pv.y);
                    o[3] = cap[3] * av[3] + cbp[3] * b2f1(pv.y >> 16);
                } else {
                    o[0] = cap[0] * av[0]; o[1] = cap[1] * av[1];
                    o[2] = cap[2] * av[2]; o[3] = cap[3] * av[3];
                }
                unsigned lo = f2b1(o[0]) | (f2b1(o[1]) << 16);
                unsigned hi = f2b1(o[2]) | (f2b1(o[3]) << 16);
                *(uint2*)&DstT[(size_t)c * LDT + bo + ib] = make_uint2(lo, hi);
            }
        }
    }
}

// ========== feature GEMM: OutT[co][m] = relu(sum_kk Zcat[m][kk]*Wt[kk][co] + bias[co]), hi/lo out ==========
__global__ __launch_bounds__(256)
void fgemm_mfma_kernel(const short* __restrict__ A0T, const short* __restrict__ ZrT,
                       const short* __restrict__ WtT, int Kp64, int KpValid, int Cpad,
                       const float* __restrict__ bias,
                       short* __restrict__ OutH, short* __restrict__ OutL) {
    __shared__ short As[128 * 64], Bs[128 * 64];
    int tid = threadIdx.x, lane = tid & 63, w = tid >> 6;
    int wr = w >> 1, wc = w & 1;
    int m0 = blockIdx.x * 128, co0 = blockIdx.y * 128;
    const unsigned short* A0 = (const unsigned short*)A0T;
    const unsigned short* Zr = (const unsigned short*)ZrT;
    f32x4 acc[4][4] = {};
    for (int kk0 = 0; kk0 < Kp64; kk0 += 64) {
        // A: transpose-stage from Zcat_t rows kk (dual source), cols m0..m0+127
        #pragma unroll
        for (int n = 0; n < 2; n++) {
            int q = n * 256 + tid;
            int p = q >> 4, h = q & 15;
            int kg0 = kk0 + 2 * p;
            uint4 r0 = make_uint4(0, 0, 0, 0), r1 = make_uint4(0, 0, 0, 0);
            if (kg0 < KpValid) {
                const unsigned short* s0 = (kg0 < Cpad) ? (A0 + (size_t)kg0 * LDT)
                                                        : (Zr + (size_t)(kg0 - Cpad) * LDT);
                r0 = *(const uint4*)&s0[m0 + 8 * h];
            }
            if (kg0 + 1 < KpValid) {
                int kg1 = kg0 + 1;
                const unsigned short* s1 = (kg1 < Cpad) ? (A0 + (size_t)kg1 * LDT)
                                                        : (Zr + (size_t)(kg1 - Cpad) * LDT);
                r1 = *(const uint4*)&s1[m0 + 8 * h];
            }
            const unsigned* a0 = (const unsigned*)&r0;
            const unsigned* a1 = (const unsigned*)&r1;
            #pragma unroll
            for (int e = 0; e < 8; e++) {
                unsigned lo = (e & 1) ? (a0[e >> 1] >> 16) : (a0[e >> 1] & 0xffffu);
                unsigned hi = (e & 1) ? (a1[e >> 1] >> 16) : (a1[e >> 1] & 0xffffu);
                int r = 8 * h + e;
                *(unsigned*)&As[SW(r, 2 * p)] = lo | (hi << 16);
            }
        }
        // B: WtT rows co0..co0+127, cols kk0..kk0+63 (zeros pre-baked)
        stage_rows(Bs, (const unsigned short*)WtT + (size_t)co0 * Kp64, Kp64, kk0, tid);
        __syncthreads();
        mfma_step(As, Bs, acc, wr, wc, lane);
        __syncthreads();
    }
    #pragma unroll
    for (int fr = 0; fr < 4; fr++) {
        int mb = m0 + wr * 64 + fr * 16 + (lane >> 4) * 4;
        #pragma unroll
        for (int fc = 0; fc < 4; fc++) {
            int co = co0 + wc * 64 + fc * 16 + (lane & 15);
            float bz = bias[co];
            const float* av = (const float*)&acc[fr][fc];
            unsigned ph[4], pl[4];
            #pragma unroll
            for (int r = 0; r < 4; r++) {
                float v = av[r] + bz;
                v = v > 0.f ? v : 0.f;
                ph[r] = f2b1(v);
                pl[r] = f2b1(v - b2f1(ph[r]));
            }
            *(uint2*)&OutH[(size_t)co * LDT + mb] = make_uint2(ph[0] | (ph[1] << 16), ph[2] | (ph[3] << 16));
            *(uint2*)&OutL[(size_t)co * LDT + mb] = make_uint2(pl[0] | (pl[1] << 16), pl[2] | (pl[3] << 16));
        }
    }
}

// ========== M partials: Mpart[z][cj][ci] = sum_{m in chunk} XT[ci][m]*VT[cj][m] ==========
__global__ __launch_bounds__(256)
void mgemm_mfma_kernel(const short* __restrict__ XT, const short* __restrict__ VT,
                       float* __restrict__ Mpart, int Cout, int kChunk) {
    __shared__ short As[128 * 64], Bs[128 * 64];
    int tid = threadIdx.x, lane = tid & 63, w = tid >> 6;
    int wr = w >> 1, wc = w & 1;
    int ci0 = blockIdx.x * 128, cj0 = blockIdx.y * 128;
    int kStart = blockIdx.z * kChunk;
    f32x4 acc[4][4] = {};
    for (int k0 = kStart; k0 < kStart + kChunk; k0 += 64) {
        stage_rows(As, (const unsigned short*)XT + (size_t)ci0 * LDT, LDT, k0, tid);
        stage_rows(Bs, (const unsigned short*)VT + (size_t)cj0 * LDT, LDT, k0, tid);
        __syncthreads();
        mfma_step(As, Bs, acc, wr, wc, lane);
        __syncthreads();
    }
    float* pt = Mpart + (size_t)blockIdx.z * Cout * Cout;
    #pragma unroll
    for (int fr = 0; fr < 4; fr++) {
        int cib = ci0 + wr * 64 + fr * 16 + (lane >> 4) * 4;
        #pragma unroll
        for (int fc = 0; fc < 4; fc++) {
            int cj = cj0 + wc * 64 + fc * 16 + (lane & 15);
            *(f32x4*)&pt[(size_t)cj * Cout + cib] = acc[fr][fc];   // transposed (norm-invariant)
        }
    }
}

// ================= Frobenius norm of summed split-K partials (deterministic) =================
__global__ void fro1_kernel(const float* __restrict__ part, int nElem, int splitk,
                            float* __restrict__ blockSS) {
    int tid = threadIdx.x;
    float ss = 0.f;
    for (int idx = blockIdx.x * 256 + tid; idx < nElem; idx += 1024 * 256) {
        float s = 0.f;
        for (int z = 0; z < splitk; z++) s += part[(size_t)z * nElem + idx];
        ss += s * s;
    }
    __shared__ float red[256];
    red[tid] = ss; __syncthreads();
    for (int m = 128; m >= 1; m >>= 1) { if (tid < m) red[tid] += red[tid + m]; __syncthreads(); }
    if (tid == 0) blockSS[blockIdx.x] = red[0];
}
__global__ void fro2_kernel(const float* __restrict__ blockSS, float* __restrict__ outp) {
    int tid = threadIdx.x;
    float s = 0.f;
    for (int i = tid; i < 1024; i += 256) s += blockSS[i];
    __shared__ float red[256];
    red[tid] = s; __syncthreads();
    for (int m = 128; m >= 1; m >>= 1) { if (tid < m) red[tid] += red[tid + m]; __syncthreads(); }
    if (tid == 0) *outp = sqrtf(red[0]);
}

// ================= max-pool over points (hi+lo reconstruct) =================
__global__ void pool_kernel(const short* __restrict__ H, const short* __restrict__ L,
                            float* __restrict__ out) {
    int b = blockIdx.x;
    int co = blockIdx.y * 256 + threadIdx.x;
    const unsigned short* h = (const unsigned short*)H + (size_t)co * LDT + b * NN;
    const unsigned short* l = (const unsigned short*)L + (size_t)co * LDT + b * NN;
    float m = -1e30f;
    for (int n = 0; n < NN; n++) m = fmaxf(m, b2f1(h[n]) + b2f1(l[n]));
    out[b * 1024 + co] = m;
}

__global__ void fc_kernel(const float* __restrict__ in, const float* __restrict__ Wt,
                          const float* __restrict__ bias, float* __restrict__ out,
                          int K, int O, int doRelu) {
    int b = blockIdx.x;
    int o = blockIdx.y * 64 + threadIdx.x;
    if (o >= O) return;
    float acc = bias[o];
    const float* ib = in + b * K;
    for (int k = 0; k < K; k++) acc += ib[k] * Wt[(size_t)k * O + o];
    if (doRelu) acc = fmaxf(acc, 0.f);
    out[b * O + o] = acc;
}

extern "C" void kernel_launch(void* const* d_in, const int* in_sizes, int n_in,
                              void* d_out, int out_size, void* d_ws, size_t ws_size,
                              hipStream_t stream) {
    const float* x   = (const float*)d_in[0];
    const float* w1  = (const float*)d_in[4];
    const float* b1  = (const float*)d_in[5];
    const float* w2  = (const float*)d_in[6];
    const float* b2  = (const float*)d_in[7];
    const float* w3  = (const float*)d_in[8];
    const float* b3  = (const float*)d_in[9];
    const float* fw1 = (const float*)d_in[10];
    const float* fb1 = (const float*)d_in[11];
    const float* fw2 = (const float*)d_in[12];
    const float* fb2 = (const float*)d_in[13];
    const float* fw3 = (const float*)d_in[14];
    const float* fb3 = (const float*)d_in[15];
    float* out = (float*)d_out;

    char* ws = (char*)d_ws;
    size_t off = 0;
    auto alloc = [&](size_t bytes) -> void* {
        void* p = ws + off; off += (bytes + 255) & ~(size_t)255; return p;
    };
    short* Wbuf = (short*)alloc((size_t)BB * NN * NN * 2);   // 32 MiB bf16 W; Mpart aliases later
    short* Zbuf = (short*)alloc((size_t)1024 * LDT * 2);     // 32 MiB Z slices; VT aliases later
    short* o1H  = (short*)alloc((size_t)128 * LDT * 2);
    short* o1L  = (short*)alloc((size_t)128 * LDT * 2);
    short* o2H  = (short*)alloc((size_t)512 * LDT * 2);
    short* o2L  = (short*)alloc((size_t)512 * LDT * 2);
    short* o3H  = (short*)alloc((size_t)1024 * LDT * 2);
    short* o3L  = (short*)alloc((size_t)1024 * LDT * 2);
    short* xTh  = (short*)alloc((size_t)8 * LDT * 2);
    short* xTl  = (short*)alloc((size_t)8 * LDT * 2);
    short* WtT  = (short*)alloc((size_t)1024 * 1536 * 2);
    float* sqpart = (float*)alloc((size_t)8 * LDT * 4);
    float* sq    = (float*)alloc(BB * NN * 4);
    float* dsum  = (float*)alloc(BB * NN * 4);
    float* dsumP = (float*)alloc(BB * NN * 4);
    float* dinv  = (float*)alloc(BB * NN * 4);
    float* dinvP = (float*)alloc(BB * NN * 4);
    float* cA1   = (float*)alloc(BB * NN * 4);
    float* cA2   = (float*)alloc(BB * NN * 4);
    float* cAV   = (float*)alloc(BB * NN * 4);
    float* cOne  = (float*)alloc(BB * NN * 4);
    float* cNeg1 = (float*)alloc(BB * NN * 4);
    float* pooled= (float*)alloc(BB * 1024 * 4);
    float* h1    = (float*)alloc(BB * 512 * 4);
    float* h2    = (float*)alloc(BB * 128 * 4);
    float* blockSS = (float*)alloc(1024 * 4);
    float* Mpart = (float*)Wbuf;      // alias: W dead after V-step
    short* VT    = Zbuf;              // alias: Z dead after fgemm
    (void)ws_size; (void)in_sizes; (void)n_in; (void)out_size;

    struct Layer {
        const short *XTh, *XTl;       // input features (transposed hi/lo)
        int C, ck64, K, Cpad, shift, Kp64, KpValid, Cout, splitk, rIdx;
        const float *Wk, *bk;
        short *OutH, *OutL;
    };
    Layer L[3] = {
        { xTh, xTl, 8,   1, 6, 8,   3, 64,   48,   128,  64, 160, w1, b1, o1H, o1L },
        { o1H, o1L, 128, 2, 5, 128, 7, 640,  640,  512,  32, 161, w2, b2, o2H, o2L },
        { o2H, o2L, 512, 8, 3, 512, 9, 1536, 1536, 1024, 8,  162, w3, b3, o3H, o3L },
    };

    xt_prep_kernel<<<LDT / 256, 256, 0, stream>>>(x, xTh, xTl);

    for (int l = 0; l < 3; l++) {
        const Layer& P = L[l];
        int NC = (P.C + 127) / 128;
        wtt_prep_kernel<<<(P.Cout * P.Kp64 + 255) / 256, 256, 0, stream>>>(
            P.Wk, WtT, P.Kp64, P.KpValid, P.Cpad - 1, P.shift, (l == 0) ? 6 : P.C, P.Cout);
        sqt_part_kernel<<<dim3(LDT / 256, NC), 256, 0, stream>>>(P.XTh, P.XTl, P.C, sqpart);
        sqt_red_kernel<<<LDT / 256, 256, 0, stream>>>(sqpart, NC, sq);
        adj_mfma_kernel<<<dim3(8, 8, BB), 256, 0, stream>>>(P.XTh, P.XTl, P.ck64, P.C, sq, Wbuf);
        rowsum_kernel<<<BB * NN / 4, 256, 0, stream>>>(Wbuf, dsum, dsumP);
        prep_kernel<<<BB * NN / 256, 256, 0, stream>>>(dsum, dsumP, dinv, dinvP, cA1, cA2, cAV, cOne, cNeg1);

        // Chebyshev: slices 1..K-1 live in Zbuf at (k-1)*Cpad rows; Z0 = P.XTh
        int cT = (P.Cpad + 127) / 128;
        auto slice = [&](int k) -> short* { return Zbuf + (size_t)(k - 1) * P.Cpad * LDT; };
        wgemm_mfma_kernel<false, false><<<dim3(8, cT, BB), 256, 0, stream>>>(
            Wbuf, dinv, P.XTh, cA1, cOne, (const short*)nullptr, slice(1), P.Cpad);
        for (int k = 2; k < P.K; k++) {
            const short* prevT = (k == 2) ? P.XTh : slice(k - 2);
            wgemm_mfma_kernel<true, false><<<dim3(8, cT, BB), 256, 0, stream>>>(
                Wbuf, dinv, slice(k - 1), cA2, cNeg1, prevT, slice(k), P.Cpad);
        }
        fgemm_mfma_kernel<<<dim3(LDT / 128, P.Cout / 128), 256, 0, stream>>>(
            P.XTh, Zbuf, WtT, P.Kp64, P.KpValid, P.Cpad, P.bk, P.OutH, P.OutL);
        // V = out - dinvP .* (W_nodiag @ (dinvP .* out)) ; VT aliases Zbuf
        wgemm_mfma_kernel<true, true><<<dim3(8, P.Cout / 128, BB), 256, 0, stream>>>(
            Wbuf, dinvP, P.OutH, cAV, cOne, P.OutH, VT, P.Cout);
        int kChunk = LDT / P.splitk;
        mgemm_mfma_kernel<<<dim3(P.Cout / 128, P.Cout / 128, P.splitk), 256, 0, stream>>>(
            P.OutH, VT, Mpart, P.Cout, kChunk);
        fro1_kernel<<<1024, 256, 0, stream>>>(Mpart, P.Cout * P.Cout, P.splitk, blockSS);
        fro2_kernel<<<1, 256, 0, stream>>>(blockSS, out + P.rIdx);
    }
    pool_kernel<<<dim3(BB, 4), 256, 0, stream>>>(o3H, o3L, pooled);
    fc_kernel<<<dim3(BB, 8), 64, 0, stream>>>(pooled, fw1, fb1, h1, 1024, 512, 1);
    fc_kernel<<<dim3(BB, 2), 64, 0, stream>>>(h1, fw2, fb2, h2, 512, 128, 1);
    fc_kernel<<<dim3(BB, 1), 64, 0, stream>>>(h2, fw3, fb3, out, 128, 10, 0);
}

// Round 5
// 1414.300 us; speedup vs baseline: 3.2189x; 1.3512x over previous
//
#include <hip/hip_runtime.h>

#define BB 16
#define NN 1024
#define LDT 16384          // column count of all transposed feature buffers

typedef float4 f4;
typedef __attribute__((ext_vector_type(8))) short bf16x8;
typedef __attribute__((ext_vector_type(4))) float f32x4;

// bf16 pack/unpack (RNE)
__device__ __forceinline__ unsigned f2b1(float f) {
    unsigned u = __builtin_bit_cast(unsigned, f);
    return (u + 0x7fffu + ((u >> 16) & 1u)) >> 16;
}
__device__ __forceinline__ float b2f1(unsigned s) {
    unsigned u = (s & 0xffffu) << 16;
    return __builtin_bit_cast(float, u);
}

// LDS tile element offset with XOR swizzle (tile is [row][k] = [128][64] shorts)
#define SW(r, k) ((r) * 64 + ((k) ^ (((r) & 7) << 3)))

__device__ __forceinline__ float wave_sum(float v) {
    #pragma unroll
    for (int m = 32; m >= 1; m >>= 1) v += __shfl_xor(v, m);
    return v;
}
__device__ __forceinline__ float wave_max(float v) {
    #pragma unroll
    for (int m = 32; m >= 1; m >>= 1) v = fmaxf(v, __shfl_xor(v, m));
    return v;
}

// ---- shared MFMA inner step: one 64-deep k-tile, 4x4 16x16 frags per wave ----
__device__ __forceinline__ void mfma_step(const short* As, const short* Bs,
                                          f32x4 (&acc)[4][4], int wr, int wc, int lane) {
    int la = lane & 15;
    #pragma unroll
    for (int ks = 0; ks < 2; ks++) {
        int kb = ks * 32 + (lane >> 4) * 8;
        bf16x8 a[4], b[4];
        #pragma unroll
        for (int f = 0; f < 4; f++) {
            int row = wr * 64 + f * 16 + la;
            a[f] = *(const bf16x8*)&As[SW(row, kb)];
        }
        #pragma unroll
        for (int f = 0; f < 4; f++) {
            int col = wc * 64 + f * 16 + la;
            b[f] = *(const bf16x8*)&Bs[SW(col, kb)];
        }
        #pragma unroll
        for (int fr = 0; fr < 4; fr++)
            #pragma unroll
            for (int fc = 0; fc < 4; fc++)
                acc[fr][fc] = __builtin_amdgcn_mfma_f32_16x16x32_bf16(a[fr], b[fc], acc[fr][fc], 0, 0, 0);
    }
}

// ---- direct row-copy staging: T[r][k] = src[r*stride + col_base + k], 128x64 ----
__device__ __forceinline__ void stage_rows(short* T, const unsigned short* src,
                                           size_t row_stride, size_t col_base, int tid) {
    #pragma unroll
    for (int n = 0; n < 4; n++) {
        int q = n * 256 + tid;
        int r = q >> 3, k8 = (q & 7) * 8;
        uint4 v = *(const uint4*)&src[(size_t)r * row_stride + col_base + k8];
        *(uint4*)&T[SW(r, k8)] = v;
    }
}

// ---- transpose staging (pair-pack): T[r=0..127][c=0..63] = src[(c0+c)*LDT + col_base + r] ----
__device__ __forceinline__ void stage_tr(short* T, const unsigned short* src,
                                         size_t col_base, int c0, int Cvalid, int tid) {
    #pragma unroll
    for (int n = 0; n < 2; n++) {
        int q = n * 256 + tid;
        int p = q >> 4, h = q & 15;
        int cg = c0 + 2 * p;
        uint4 r0 = make_uint4(0, 0, 0, 0), r1 = make_uint4(0, 0, 0, 0);
        if (cg < Cvalid)     r0 = *(const uint4*)&src[(size_t)cg * LDT + col_base + 8 * h];
        if (cg + 1 < Cvalid) r1 = *(const uint4*)&src[(size_t)(cg + 1) * LDT + col_base + 8 * h];
        const unsigned* a0 = (const unsigned*)&r0;
        const unsigned* a1 = (const unsigned*)&r1;
        #pragma unroll
        for (int e = 0; e < 8; e++) {
            unsigned lo = (e & 1) ? (a0[e >> 1] >> 16) : (a0[e >> 1] & 0xffffu);
            unsigned hi = (e & 1) ? (a1[e >> 1] >> 16) : (a1[e >> 1] & 0xffffu);
            int r = 8 * h + e;
            *(unsigned*)&T[SW(r, 2 * p)] = lo | (hi << 16);
        }
    }
}

// ================= input prep =================
__global__ void xt_prep_kernel(const float* __restrict__ x, short* __restrict__ xh,
                               short* __restrict__ xl) {
    int m = blockIdx.x * 256 + threadIdx.x;
    #pragma unroll
    for (int c = 0; c < 8; c++) {
        float v = (c < 6) ? x[(size_t)m * 6 + c] : 0.f;
        unsigned h = f2b1(v);
        unsigned l = f2b1(v - b2f1(h));
        xh[(size_t)c * LDT + m] = (short)h;
        xl[(size_t)c * LDT + m] = (short)l;
    }
}

__global__ void wtt_prep_kernel(const float* __restrict__ Wk, short* __restrict__ WtT,
                                int Kp64, int KpValid, int CpadM1, int shift, int Cin, int Cout) {
    int idx = blockIdx.x * 256 + threadIdx.x;
    if (idx >= Cout * Kp64) return;
    int co = idx / Kp64, kk = idx - co * Kp64;
    int c = kk & CpadM1;
    float val = 0.f;
    if (kk < KpValid && c < Cin)
        val = Wk[((size_t)(kk >> shift) * Cin + c) * Cout + co];
    WtT[(size_t)co * Kp64 + kk] = (short)f2b1(val);
}

// ---- FC weight transpose: WtT[o][k] = Wt[k][o] ----
__global__ void wtrans_kernel(const float* __restrict__ Wt, float* __restrict__ WtT,
                              int K, int O) {
    int idx = blockIdx.x * 256 + threadIdx.x;
    if (idx >= K * O) return;
    int o = idx / K, k = idx - o * K;
    WtT[idx] = Wt[(size_t)k * O + o];
}

// ================= squared norms from hi/lo (partial over 128-c chunks) =================
__global__ void sqt_part_kernel(const short* __restrict__ H, const short* __restrict__ L,
                                int C, float* __restrict__ dst) {
    int m = blockIdx.x * 256 + threadIdx.x;
    int cb = blockIdx.y * 128;
    int ce = min(cb + 128, C);
    const unsigned short* Hp = (const unsigned short*)H;
    const unsigned short* Lp = (const unsigned short*)L;
    float s = 0.f;
    for (int c = cb; c < ce; c++) {
        float v = b2f1(Hp[(size_t)c * LDT + m]) + b2f1(Lp[(size_t)c * LDT + m]);
        s += v * v;
    }
    dst[(size_t)blockIdx.y * LDT + m] = s;
}
__global__ void sqt_red_kernel(const float* __restrict__ part, int NC, float* __restrict__ sq) {
    int m = blockIdx.x * 256 + threadIdx.x;
    float s = 0.f;
    for (int y = 0; y < NC; y++) s += part[(size_t)y * LDT + m];
    sq[m] = s;
}

// ================= adjacency: W[b][j][i] = exp(2G - sq_i - sq_j), hi/lo 3-term MFMA =================
__global__ __launch_bounds__(256)
void adj_mfma_kernel(const short* __restrict__ XTh, const short* __restrict__ XTl,
                     int ck64, int Cvalid, const float* __restrict__ sq,
                     short* __restrict__ Wb) {
    __shared__ short Ah[128 * 64], Al[128 * 64], Bh[128 * 64], Bl[128 * 64];
    int tid = threadIdx.x, lane = tid & 63, w = tid >> 6;
    int wr = w >> 1, wc = w & 1;
    int b = blockIdx.z, i0 = blockIdx.x * 128, j0 = blockIdx.y * 128;
    size_t bo = (size_t)b * NN;
    f32x4 acc[4][4] = {};
    const unsigned short* Hs = (const unsigned short*)XTh;
    const unsigned short* Ls = (const unsigned short*)XTl;
    for (int t = 0; t < ck64; t++) {
        int c0 = t * 64;
        stage_tr(Ah, Hs, bo + i0, c0, Cvalid, tid);
        stage_tr(Al, Ls, bo + i0, c0, Cvalid, tid);
        stage_tr(Bh, Hs, bo + j0, c0, Cvalid, tid);
        stage_tr(Bl, Ls, bo + j0, c0, Cvalid, tid);
        __syncthreads();
        int la = lane & 15;
        #pragma unroll
        for (int ks = 0; ks < 2; ks++) {
            int kb = ks * 32 + (lane >> 4) * 8;
            bf16x8 ah[4], al[4], bh[4], bl[4];
            #pragma unroll
            for (int f = 0; f < 4; f++) {
                int row = wr * 64 + f * 16 + la;
                ah[f] = *(const bf16x8*)&Ah[SW(row, kb)];
                al[f] = *(const bf16x8*)&Al[SW(row, kb)];
                int col = wc * 64 + f * 16 + la;
                bh[f] = *(const bf16x8*)&Bh[SW(col, kb)];
                bl[f] = *(const bf16x8*)&Bl[SW(col, kb)];
            }
            #pragma unroll
            for (int fr = 0; fr < 4; fr++)
                #pragma unroll
                for (int fc = 0; fc < 4; fc++) {
                    acc[fr][fc] = __builtin_amdgcn_mfma_f32_16x16x32_bf16(ah[fr], bh[fc], acc[fr][fc], 0, 0, 0);
                    acc[fr][fc] = __builtin_amdgcn_mfma_f32_16x16x32_bf16(ah[fr], bl[fc], acc[fr][fc], 0, 0, 0);
                    acc[fr][fc] = __builtin_amdgcn_mfma_f32_16x16x32_bf16(al[fr], bh[fc], acc[fr][fc], 0, 0, 0);
                }
        }
        __syncthreads();
    }
    const float* sqb = sq + bo;
    short* Wout = Wb + bo * NN;
    #pragma unroll
    for (int fr = 0; fr < 4; fr++) {
        int ib = i0 + wr * 64 + fr * 16 + (lane >> 4) * 4;
        f4 si = *(const f4*)&sqb[ib];
        const float* sip = (const float*)&si;
        #pragma unroll
        for (int fc = 0; fc < 4; fc++) {
            int jb = j0 + wc * 64 + fc * 16 + (lane & 15);
            float sj = sqb[jb];
            const float* av = (const float*)&acc[fr][fc];
            unsigned lo = f2b1(__expf(2.f * av[0] - sip[0] - sj)) |
                          (f2b1(__expf(2.f * av[1] - sip[1] - sj)) << 16);
            unsigned hi = f2b1(__expf(2.f * av[2] - sip[2] - sj)) |
                          (f2b1(__expf(2.f * av[3] - sip[3] - sj)) << 16);
            // symmetric trick: write row jb, cols ib..ib+3 (coalesced 8B)
            *(uint2*)&Wout[(size_t)jb * NN + ib] = make_uint2(lo, hi);
        }
    }
}

// ================= row sums (bf16 W, diag excluded by index, fp32 accum) =================
__global__ void rowsum_kernel(const short* __restrict__ W, float* __restrict__ dsum,
                              float* __restrict__ dsumP) {
    int wave = threadIdx.x >> 6, lane = threadIdx.x & 63;
    int row = blockIdx.x * 4 + wave;          // global b*NN+i
    int i = row & (NN - 1);
    const unsigned short* Wr = (const unsigned short*)W + (size_t)row * NN;
    float part = 0.f, diag = 0.f;
    #pragma unroll
    for (int it = 0; it < 2; it++) {
        int j8 = (it * 64 + lane) * 8;
        uint4 v = *(const uint4*)&Wr[j8];
        const unsigned* vp = (const unsigned*)&v;
        #pragma unroll
        for (int e = 0; e < 4; e++) {
            float lo = b2f1(vp[e]), hi = b2f1(vp[e] >> 16);
            if (j8 + 2 * e == i)     { diag += lo; lo = 0.f; }
            if (j8 + 2 * e + 1 == i) { diag += hi; hi = 0.f; }
            part += lo + hi;
        }
    }
    part = wave_sum(part);
    diag = wave_sum(diag);
    if (lane == 0) { dsumP[row] = part; dsum[row] = part + diag; }
}

__global__ void prep_kernel(const float* __restrict__ dsum, const float* __restrict__ dsumP,
                            float* dinv, float* dinvP, float* cA1, float* cA2,
                            float* cAV, float* cOne, float* cNeg1) {
    int i = blockIdx.x * 256 + threadIdx.x;
    float dv = rsqrtf(dsum[i]);
    float dp = rsqrtf(dsumP[i]);
    dinv[i] = dv; dinvP[i] = dp;
    cA1[i] = -dv; cA2[i] = -2.f * dv;
    cAV[i] = -dp; cOne[i] = 1.f; cNeg1[i] = -1.f;
}

// ========== W-GEMM: DstT[c][i] = cA_i * sum_j W[i][j]*sIn_j*ZinT[c][j] (+ cB_i*PrevT[c][i]) ==========
template<bool HAS_PREV, bool SKIP_DIAG>
__global__ __launch_bounds__(256)
void wgemm_mfma_kernel(const short* __restrict__ W, const float* __restrict__ sIn,
                       const short* __restrict__ ZinT,
                       const float* __restrict__ cA, const float* __restrict__ cB,
                       const short* __restrict__ PrevT, short* __restrict__ DstT,
                       int Cvalid) {
    __shared__ short As[128 * 64], Bs[128 * 64];
    int tid = threadIdx.x, lane = tid & 63, w = tid >> 6;
    int wr = w >> 1, wc = w & 1;
    int b = blockIdx.z, i0 = blockIdx.x * 128, c0t = blockIdx.y * 128;
    size_t bo = (size_t)b * NN;
    const unsigned short* Wp = (const unsigned short*)W + bo * NN;
    const unsigned short* Zp = (const unsigned short*)ZinT;
    f32x4 acc[4][4] = {};
    for (int k0 = 0; k0 < NN; k0 += 64) {
        // A: W rows i0..i0+127, cols k0..k0+63 (optional diag zero)
        #pragma unroll
        for (int n = 0; n < 4; n++) {
            int q = n * 256 + tid;
            int r = q >> 3, k8 = (q & 7) * 8;
            uint4 v = *(const uint4*)&Wp[(size_t)(i0 + r) * NN + k0 + k8];
            if (SKIP_DIAG) {
                int d = (i0 + r) - (k0 + k8);
                if ((unsigned)d < 8u) {
                    unsigned* vp = (unsigned*)&v;
                    vp[d >> 1] &= (d & 1) ? 0x0000ffffu : 0xffff0000u;
                }
            }
            *(uint4*)&As[SW(r, k8)] = v;
        }
        // B: ZinT rows (channels), cols = points k0.. scaled by sIn
        #pragma unroll
        for (int n = 0; n < 4; n++) {
            int q = n * 256 + tid;
            int c = q >> 3, j8 = (q & 7) * 8;
            uint4 v = make_uint4(0, 0, 0, 0);
            if (c0t + c < Cvalid) {
                uint4 raw = *(const uint4*)&Zp[(size_t)(c0t + c) * LDT + bo + k0 + j8];
                f4 s0 = *(const f4*)&sIn[bo + k0 + j8];
                f4 s1 = *(const f4*)&sIn[bo + k0 + j8 + 4];
                const unsigned* rp = (const unsigned*)&raw;
                const float* sp0 = (const float*)&s0;
                const float* sp1 = (const float*)&s1;
                unsigned* vp = (unsigned*)&v;
                #pragma unroll
                for (int e = 0; e < 4; e++) {
                    float se0 = (e < 2) ? sp0[2 * e] : sp1[2 * e - 4];
                    float se1 = (e < 2) ? sp0[2 * e + 1] : sp1[2 * e - 3];
                    vp[e] = f2b1(b2f1(rp[e]) * se0) | (f2b1(b2f1(rp[e] >> 16) * se1) << 16);
                }
            }
            *(uint4*)&Bs[SW(c, j8)] = v;
        }
        __syncthreads();
        mfma_step(As, Bs, acc, wr, wc, lane);
        __syncthreads();
    }
    const float* cAb = cA + bo;
    const float* cBb = cB + bo;
    #pragma unroll
    for (int fr = 0; fr < 4; fr++) {
        int ib = i0 + wr * 64 + fr * 16 + (lane >> 4) * 4;
        f4 ca = *(const f4*)&cAb[ib];
        const float* cap = (const float*)&ca;
        f4 cb;
        const float* cbp = (const float*)&cb;
        if (HAS_PREV) cb = *(const f4*)&cBb[ib];
        #pragma unroll
        for (int fc = 0; fc < 4; fc++) {
            int c = c0t + wc * 64 + fc * 16 + (lane & 15);
            if (c < Cvalid) {
                const float* av = (const float*)&acc[fr][fc];
                float o[4];
                if (HAS_PREV) {
                    uint2 pv = *(const uint2*)&PrevT[(size_t)c * LDT + bo + ib];
                    o[0] = cap[0] * av[0] + cbp[0] * b2f1(pv.x);
                    o[1] = cap[1] * av[1] + cbp[1] * b2f1(pv.x >> 16);
                    o[2] = cap[2] * av[2] + cbp[2] * b2f1(pv.y);
                    o[3] = cap[3] * av[3] + cbp[3] * b2f1(pv.y >> 16);
                } else {
                    o[0] = cap[0] * av[0]; o[1] = cap[1] * av[1];
                    o[2] = cap[2] * av[2]; o[3] = cap[3] * av[3];
                }
                unsigned lo = f2b1(o[0]) | (f2b1(o[1]) << 16);
                unsigned hi = f2b1(o[2]) | (f2b1(o[3]) << 16);
                *(uint2*)&DstT[(size_t)c * LDT + bo + ib] = make_uint2(lo, hi);
            }
        }
    }
}

// ========== feature GEMM: OutT[co][m] = relu(sum_kk Zcat[m][kk]*Wt[kk][co] + bias[co]), hi/lo out ==========
__global__ __launch_bounds__(256)
void fgemm_mfma_kernel(const short* __restrict__ A0T, const short* __restrict__ ZrT,
                       const short* __restrict__ WtT, int Kp64, int KpValid, int Cpad,
                       const float* __restrict__ bias,
                       short* __restrict__ OutH, short* __restrict__ OutL) {
    __shared__ short As[128 * 64], Bs[128 * 64];
    int tid = threadIdx.x, lane = tid & 63, w = tid >> 6;
    int wr = w >> 1, wc = w & 1;
    int m0 = blockIdx.x * 128, co0 = blockIdx.y * 128;
    const unsigned short* A0 = (const unsigned short*)A0T;
    const unsigned short* Zr = (const unsigned short*)ZrT;
    f32x4 acc[4][4] = {};
    for (int kk0 = 0; kk0 < Kp64; kk0 += 64) {
        // A: transpose-stage from Zcat_t rows kk (dual source), cols m0..m0+127
        #pragma unroll
        for (int n = 0; n < 2; n++) {
            int q = n * 256 + tid;
            int p = q >> 4, h = q & 15;
            int kg0 = kk0 + 2 * p;
            uint4 r0 = make_uint4(0, 0, 0, 0), r1 = make_uint4(0, 0, 0, 0);
            if (kg0 < KpValid) {
                const unsigned short* s0 = (kg0 < Cpad) ? (A0 + (size_t)kg0 * LDT)
                                                        : (Zr + (size_t)(kg0 - Cpad) * LDT);
                r0 = *(const uint4*)&s0[m0 + 8 * h];
            }
            if (kg0 + 1 < KpValid) {
                int kg1 = kg0 + 1;
                const unsigned short* s1 = (kg1 < Cpad) ? (A0 + (size_t)kg1 * LDT)
                                                        : (Zr + (size_t)(kg1 - Cpad) * LDT);
                r1 = *(const uint4*)&s1[m0 + 8 * h];
            }
            const unsigned* a0 = (const unsigned*)&r0;
            const unsigned* a1 = (const unsigned*)&r1;
            #pragma unroll
            for (int e = 0; e < 8; e++) {
                unsigned lo = (e & 1) ? (a0[e >> 1] >> 16) : (a0[e >> 1] & 0xffffu);
                unsigned hi = (e & 1) ? (a1[e >> 1] >> 16) : (a1[e >> 1] & 0xffffu);
                int r = 8 * h + e;
                *(unsigned*)&As[SW(r, 2 * p)] = lo | (hi << 16);
            }
        }
        // B: WtT rows co0..co0+127, cols kk0..kk0+63 (zeros pre-baked)
        stage_rows(Bs, (const unsigned short*)WtT + (size_t)co0 * Kp64, Kp64, kk0, tid);
        __syncthreads();
        mfma_step(As, Bs, acc, wr, wc, lane);
        __syncthreads();
    }
    #pragma unroll
    for (int fr = 0; fr < 4; fr++) {
        int mb = m0 + wr * 64 + fr * 16 + (lane >> 4) * 4;
        #pragma unroll
        for (int fc = 0; fc < 4; fc++) {
            int co = co0 + wc * 64 + fc * 16 + (lane & 15);
            float bz = bias[co];
            const float* av = (const float*)&acc[fr][fc];
            unsigned ph[4], pl[4];
            #pragma unroll
            for (int r = 0; r < 4; r++) {
                float v = av[r] + bz;
                v = v > 0.f ? v : 0.f;
                ph[r] = f2b1(v);
                pl[r] = f2b1(v - b2f1(ph[r]));
            }
            *(uint2*)&OutH[(size_t)co * LDT + mb] = make_uint2(ph[0] | (ph[1] << 16), ph[2] | (ph[3] << 16));
            *(uint2*)&OutL[(size_t)co * LDT + mb] = make_uint2(pl[0] | (pl[1] << 16), pl[2] | (pl[3] << 16));
        }
    }
}

// ========== M partials: Mpart[z][cj][ci] = sum_{m in chunk} XT[ci][m]*VT[cj][m] ==========
__global__ __launch_bounds__(256)
void mgemm_mfma_kernel(const short* __restrict__ XT, const short* __restrict__ VT,
                       float* __restrict__ Mpart, int Cout, int kChunk) {
    __shared__ short As[128 * 64], Bs[128 * 64];
    int tid = threadIdx.x, lane = tid & 63, w = tid >> 6;
    int wr = w >> 1, wc = w & 1;
    int ci0 = blockIdx.x * 128, cj0 = blockIdx.y * 128;
    int kStart = blockIdx.z * kChunk;
    f32x4 acc[4][4] = {};
    for (int k0 = kStart; k0 < kStart + kChunk; k0 += 64) {
        stage_rows(As, (const unsigned short*)XT + (size_t)ci0 * LDT, LDT, k0, tid);
        stage_rows(Bs, (const unsigned short*)VT + (size_t)cj0 * LDT, LDT, k0, tid);
        __syncthreads();
        mfma_step(As, Bs, acc, wr, wc, lane);
        __syncthreads();
    }
    float* pt = Mpart + (size_t)blockIdx.z * Cout * Cout;
    #pragma unroll
    for (int fr = 0; fr < 4; fr++) {
        int cib = ci0 + wr * 64 + fr * 16 + (lane >> 4) * 4;
        #pragma unroll
        for (int fc = 0; fc < 4; fc++) {
            int cj = cj0 + wc * 64 + fc * 16 + (lane & 15);
            *(f32x4*)&pt[(size_t)cj * Cout + cib] = acc[fr][fc];   // transposed (norm-invariant)
        }
    }
}

// ================= Frobenius norm of summed split-K partials (deterministic) =================
__global__ void fro1_kernel(const float* __restrict__ part, int nElem, int splitk,
                            float* __restrict__ blockSS) {
    int tid = threadIdx.x;
    float ss = 0.f;
    for (int idx = blockIdx.x * 256 + tid; idx < nElem; idx += 1024 * 256) {
        float s = 0.f;
        for (int z = 0; z < splitk; z++) s += part[(size_t)z * nElem + idx];
        ss += s * s;
    }
    __shared__ float red[256];
    red[tid] = ss; __syncthreads();
    for (int m = 128; m >= 1; m >>= 1) { if (tid < m) red[tid] += red[tid + m]; __syncthreads(); }
    if (tid == 0) blockSS[blockIdx.x] = red[0];
}
__global__ void fro2_kernel(const float* __restrict__ blockSS, float* __restrict__ outp) {
    int tid = threadIdx.x;
    float s = 0.f;
    for (int i = tid; i < 1024; i += 256) s += blockSS[i];
    __shared__ float red[256];
    red[tid] = s; __syncthreads();
    for (int m = 128; m >= 1; m >>= 1) { if (tid < m) red[tid] += red[tid + m]; __syncthreads(); }
    if (tid == 0) *outp = sqrtf(red[0]);
}

// ================= max-pool over points: one wave per (b,co) row, coalesced =================
__global__ void pool_kernel(const short* __restrict__ H, const short* __restrict__ L,
                            float* __restrict__ out) {
    int wave = threadIdx.x >> 6, lane = threadIdx.x & 63;
    int r = blockIdx.x * 4 + wave;             // [0, 16384): r = co*16 + b
    int co = r >> 4, b = r & 15;
    const unsigned short* h = (const unsigned short*)H + (size_t)co * LDT + b * NN;
    const unsigned short* l = (const unsigned short*)L + (size_t)co * LDT + b * NN;
    float m = -1e30f;
    #pragma unroll
    for (int it = 0; it < 2; it++) {
        int n8 = (it * 64 + lane) * 8;
        uint4 vh = *(const uint4*)&h[n8];
        uint4 vl = *(const uint4*)&l[n8];
        const unsigned* hp = (const unsigned*)&vh;
        const unsigned* lp = (const unsigned*)&vl;
        #pragma unroll
        for (int e = 0; e < 4; e++) {
            m = fmaxf(m, b2f1(hp[e]) + b2f1(lp[e]));
            m = fmaxf(m, b2f1(hp[e] >> 16) + b2f1(lp[e] >> 16));
        }
    }
    m = wave_max(m);
    if (lane == 0) out[b * 1024 + co] = m;
}

// ================= small FC: one wave per (b,o) output, lanes stride K (coalesced) =================
__global__ void fc_kernel(const float* __restrict__ in, const float* __restrict__ WtT,
                          const float* __restrict__ bias, float* __restrict__ out,
                          int K, int O, int doRelu) {
    int wave = threadIdx.x >> 6, lane = threadIdx.x & 63;
    int idx = blockIdx.x * 4 + wave;           // [0, 16*O)
    if (idx >= 16 * O) return;                 // guard: grid may be over-provisioned
    int b = idx / O, o = idx - b * O;
    const float* ib = in + (size_t)b * K;
    const float* wr = WtT + (size_t)o * K;
    float s = 0.f;
    for (int k = lane * 4; k < K; k += 256) {
        f4 a = *(const f4*)&ib[k];
        f4 wv = *(const f4*)&wr[k];
        s += a.x * wv.x + a.y * wv.y + a.z * wv.z + a.w * wv.w;
    }
    s = wave_sum(s);
    if (lane == 0) {
        s += bias[o];
        if (doRelu) s = fmaxf(s, 0.f);
        out[(size_t)b * O + o] = s;
    }
}

extern "C" void kernel_launch(void* const* d_in, const int* in_sizes, int n_in,
                              void* d_out, int out_size, void* d_ws, size_t ws_size,
                              hipStream_t stream) {
    const float* x   = (const float*)d_in[0];
    const float* w1  = (const float*)d_in[4];
    const float* b1  = (const float*)d_in[5];
    const float* w2  = (const float*)d_in[6];
    const float* b2  = (const float*)d_in[7];
    const float* w3  = (const float*)d_in[8];
    const float* b3  = (const float*)d_in[9];
    const float* fw1 = (const float*)d_in[10];
    const float* fb1 = (const float*)d_in[11];
    const float* fw2 = (const float*)d_in[12];
    const float* fb2 = (const float*)d_in[13];
    const float* fw3 = (const float*)d_in[14];
    const float* fb3 = (const float*)d_in[15];
    float* out = (float*)d_out;

    char* ws = (char*)d_ws;
    size_t off = 0;
    auto alloc = [&](size_t bytes) -> void* {
        void* p = ws + off; off += (bytes + 255) & ~(size_t)255; return p;
    };
    short* Wbuf = (short*)alloc((size_t)BB * NN * NN * 2);   // 32 MiB bf16 W; Mpart aliases later
    short* Zbuf = (short*)alloc((size_t)1024 * LDT * 2);     // 32 MiB Z slices; VT aliases later
    short* o1H  = (short*)alloc((size_t)128 * LDT * 2);
    short* o1L  = (short*)alloc((size_t)128 * LDT * 2);
    short* o2H  = (short*)alloc((size_t)512 * LDT * 2);
    short* o2L  = (short*)alloc((size_t)512 * LDT * 2);
    short* o3H  = (short*)alloc((size_t)1024 * LDT * 2);
    short* o3L  = (short*)alloc((size_t)1024 * LDT * 2);
    short* xTh  = (short*)alloc((size_t)8 * LDT * 2);
    short* xTl  = (short*)alloc((size_t)8 * LDT * 2);
    short* WtT  = (short*)alloc((size_t)1024 * 1536 * 2);
    float* fwT1 = (float*)alloc((size_t)512 * 1024 * 4);
    float* fwT2 = (float*)alloc((size_t)128 * 512 * 4);
    float* fwT3 = (float*)alloc((size_t)10 * 128 * 4);
    float* sqpart = (float*)alloc((size_t)8 * LDT * 4);
    float* sq    = (float*)alloc(BB * NN * 4);
    float* dsum  = (float*)alloc(BB * NN * 4);
    float* dsumP = (float*)alloc(BB * NN * 4);
    float* dinv  = (float*)alloc(BB * NN * 4);
    float* dinvP = (float*)alloc(BB * NN * 4);
    float* cA1   = (float*)alloc(BB * NN * 4);
    float* cA2   = (float*)alloc(BB * NN * 4);
    float* cAV   = (float*)alloc(BB * NN * 4);
    float* cOne  = (float*)alloc(BB * NN * 4);
    float* cNeg1 = (float*)alloc(BB * NN * 4);
    float* pooled= (float*)alloc(BB * 1024 * 4);
    float* h1    = (float*)alloc(BB * 512 * 4);
    float* h2    = (float*)alloc(BB * 128 * 4);
    float* blockSS = (float*)alloc(1024 * 4);
    float* Mpart = (float*)Wbuf;      // alias: W dead after V-step
    short* VT    = Zbuf;              // alias: Z dead after fgemm
    (void)ws_size; (void)in_sizes; (void)n_in; (void)out_size;

    struct Layer {
        const short *XTh, *XTl;       // input features (transposed hi/lo)
        int C, ck64, K, Cpad, shift, Kp64, KpValid, Cout, splitk, rIdx;
        const float *Wk, *bk;
        short *OutH, *OutL;
    };
    Layer L[3] = {
        { xTh, xTl, 8,   1, 6, 8,   3, 64,   48,   128,  64, 160, w1, b1, o1H, o1L },
        { o1H, o1L, 128, 2, 5, 128, 7, 640,  640,  512,  32, 161, w2, b2, o2H, o2L },
        { o2H, o2L, 512, 8, 3, 512, 9, 1536, 1536, 1024, 8,  162, w3, b3, o3H, o3L },
    };

    xt_prep_kernel<<<LDT / 256, 256, 0, stream>>>(x, xTh, xTl);
    wtrans_kernel<<<(1024 * 512 + 255) / 256, 256, 0, stream>>>(fw1, fwT1, 1024, 512);
    wtrans_kernel<<<(512 * 128 + 255) / 256, 256, 0, stream>>>(fw2, fwT2, 512, 128);
    wtrans_kernel<<<(128 * 10 + 255) / 256, 256, 0, stream>>>(fw3, fwT3, 128, 10);

    for (int l = 0; l < 3; l++) {
        const Layer& P = L[l];
        int NC = (P.C + 127) / 128;
        wtt_prep_kernel<<<(P.Cout * P.Kp64 + 255) / 256, 256, 0, stream>>>(
            P.Wk, WtT, P.Kp64, P.KpValid, P.Cpad - 1, P.shift, (l == 0) ? 6 : P.C, P.Cout);
        sqt_part_kernel<<<dim3(LDT / 256, NC), 256, 0, stream>>>(P.XTh, P.XTl, P.C, sqpart);
        sqt_red_kernel<<<LDT / 256, 256, 0, stream>>>(sqpart, NC, sq);
        adj_mfma_kernel<<<dim3(8, 8, BB), 256, 0, stream>>>(P.XTh, P.XTl, P.ck64, P.C, sq, Wbuf);
        rowsum_kernel<<<BB * NN / 4, 256, 0, stream>>>(Wbuf, dsum, dsumP);
        prep_kernel<<<BB * NN / 256, 256, 0, stream>>>(dsum, dsumP, dinv, dinvP, cA1, cA2, cAV, cOne, cNeg1);

        // Chebyshev: slices 1..K-1 live in Zbuf at (k-1)*Cpad rows; Z0 = P.XTh
        int cT = (P.Cpad + 127) / 128;
        auto slice = [&](int k) -> short* { return Zbuf + (size_t)(k - 1) * P.Cpad * LDT; };
        wgemm_mfma_kernel<false, false><<<dim3(8, cT, BB), 256, 0, stream>>>(
            Wbuf, dinv, P.XTh, cA1, cOne, (const short*)nullptr, slice(1), P.Cpad);
        for (int k = 2; k < P.K; k++) {
            const short* prevT = (k == 2) ? P.XTh : slice(k - 2);
            wgemm_mfma_kernel<true, false><<<dim3(8, cT, BB), 256, 0, stream>>>(
                Wbuf, dinv, slice(k - 1), cA2, cNeg1, prevT, slice(k), P.Cpad);
        }
        fgemm_mfma_kernel<<<dim3(LDT / 128, P.Cout / 128), 256, 0, stream>>>(
            P.XTh, Zbuf, WtT, P.Kp64, P.KpValid, P.Cpad, P.bk, P.OutH, P.OutL);
        // V = out - dinvP .* (W_nodiag @ (dinvP .* out)) ; VT aliases Zbuf
        wgemm_mfma_kernel<true, true><<<dim3(8, P.Cout / 128, BB), 256, 0, stream>>>(
            Wbuf, dinvP, P.OutH, cAV, cOne, P.OutH, VT, P.Cout);
        int kChunk = LDT / P.splitk;
        mgemm_mfma_kernel<<<dim3(P.Cout / 128, P.Cout / 128, P.splitk), 256, 0, stream>>>(
            P.OutH, VT, Mpart, P.Cout, kChunk);
        fro1_kernel<<<1024, 256, 0, stream>>>(Mpart, P.Cout * P.Cout, P.splitk, blockSS);
        fro2_kernel<<<1, 256, 0, stream>>>(blockSS, out + P.rIdx);
    }
    pool_kernel<<<16384 / 4, 256, 0, stream>>>(o3H, o3L, pooled);
    fc_kernel<<<(16 * 512 + 3) / 4, 256, 0, stream>>>(pooled, fwT1, fb1, h1, 1024, 512, 1);
    fc_kernel<<<(16 * 128 + 3) / 4, 256, 0, stream>>>(h1, fwT2, fb2, h2, 512, 128, 1);
    fc_kernel<<<(16 * 10 + 3) / 4, 256, 0, stream>>>(h2, fwT3, fb3, out, 128, 10, 0);
}

// Round 6
// 1221.563 us; speedup vs baseline: 3.7268x; 1.1578x over previous
//
#include <hip/hip_runtime.h>

#define BB 16
#define NN 1024
#define LDT 16384          // column count of all transposed feature buffers

typedef float4 f4;
typedef __attribute__((ext_vector_type(8))) short bf16x8;
typedef __attribute__((ext_vector_type(4))) float f32x4;

// bf16 pack/unpack (RNE)
__device__ __forceinline__ unsigned f2b1(float f) {
    unsigned u = __builtin_bit_cast(unsigned, f);
    return (u + 0x7fffu + ((u >> 16) & 1u)) >> 16;
}
__device__ __forceinline__ float b2f1(unsigned s) {
    unsigned u = (s & 0xffffu) << 16;
    return __builtin_bit_cast(float, u);
}

// LDS tile element offset with XOR swizzle (tile is [row][k] = [128][64] shorts)
#define SW(r, k) ((r) * 64 + ((k) ^ (((r) & 7) << 3)))

__device__ __forceinline__ float wave_sum(float v) {
    #pragma unroll
    for (int m = 32; m >= 1; m >>= 1) v += __shfl_xor(v, m);
    return v;
}
__device__ __forceinline__ float wave_max(float v) {
    #pragma unroll
    for (int m = 32; m >= 1; m >>= 1) v = fmaxf(v, __shfl_xor(v, m));
    return v;
}

// ---- transpose staging (pair-pack): T[r=0..127][c=0..63] = src[(c0+c)*LDT + col_base + r] ----
__device__ __forceinline__ void stage_tr(short* T, const unsigned short* src,
                                         size_t col_base, int c0, int Cvalid, int tid) {
    #pragma unroll
    for (int n = 0; n < 2; n++) {
        int q = n * 256 + tid;
        int p = q >> 4, h = q & 15;
        int cg = c0 + 2 * p;
        uint4 r0 = make_uint4(0, 0, 0, 0), r1 = make_uint4(0, 0, 0, 0);
        if (cg < Cvalid)     r0 = *(const uint4*)&src[(size_t)cg * LDT + col_base + 8 * h];
        if (cg + 1 < Cvalid) r1 = *(const uint4*)&src[(size_t)(cg + 1) * LDT + col_base + 8 * h];
        const unsigned* a0 = (const unsigned*)&r0;
        const unsigned* a1 = (const unsigned*)&r1;
        #pragma unroll
        for (int e = 0; e < 8; e++) {
            unsigned lo = (e & 1) ? (a0[e >> 1] >> 16) : (a0[e >> 1] & 0xffffu);
            unsigned hi = (e & 1) ? (a1[e >> 1] >> 16) : (a1[e >> 1] & 0xffffu);
            int r = 8 * h + e;
            *(unsigned*)&T[SW(r, 2 * p)] = lo | (hi << 16);
        }
    }
}

// ================= input prep =================
__global__ void xt_prep_kernel(const float* __restrict__ x, short* __restrict__ xh,
                               short* __restrict__ xl) {
    int m = blockIdx.x * 256 + threadIdx.x;
    #pragma unroll
    for (int c = 0; c < 8; c++) {
        float v = (c < 6) ? x[(size_t)m * 6 + c] : 0.f;
        unsigned h = f2b1(v);
        unsigned l = f2b1(v - b2f1(h));
        xh[(size_t)c * LDT + m] = (short)h;
        xl[(size_t)c * LDT + m] = (short)l;
    }
}

__global__ void wtt_prep_kernel(const float* __restrict__ Wk, short* __restrict__ WtT,
                                int Kp64, int KpValid, int CpadM1, int shift, int Cin, int Cout) {
    int idx = blockIdx.x * 256 + threadIdx.x;
    if (idx >= Cout * Kp64) return;
    int co = idx / Kp64, kk = idx - co * Kp64;
    int c = kk & CpadM1;
    float val = 0.f;
    if (kk < KpValid && c < Cin)
        val = Wk[((size_t)(kk >> shift) * Cin + c) * Cout + co];
    WtT[(size_t)co * Kp64 + kk] = (short)f2b1(val);
}

// ---- FC weight transpose: WtT[o][k] = Wt[k][o] ----
__global__ void wtrans_kernel(const float* __restrict__ Wt, float* __restrict__ WtT,
                              int K, int O) {
    int idx = blockIdx.x * 256 + threadIdx.x;
    if (idx >= K * O) return;
    int o = idx / K, k = idx - o * K;
    WtT[idx] = Wt[(size_t)k * O + o];
}

// ---- scaled copy: dst[c][m] = bf16( src[c][m] * coeff[m] ) ----
__global__ void scale_sc_kernel(const short* __restrict__ src, const float* __restrict__ coeff,
                                short* __restrict__ dst, int total8) {
    int q = blockIdx.x * 256 + threadIdx.x;
    if (q >= total8) return;
    size_t base = (size_t)q * 8;
    int m8 = (int)(base & (LDT - 1));
    uint4 v = *(const uint4*)&((const unsigned short*)src)[base];
    f4 c0 = *(const f4*)&coeff[m8];
    f4 c1 = *(const f4*)&coeff[m8 + 4];
    const float* cp0 = (const float*)&c0;
    const float* cp1 = (const float*)&c1;
    unsigned* vp = (unsigned*)&v;
    #pragma unroll
    for (int e = 0; e < 4; e++) {
        float se0 = (e < 2) ? cp0[2 * e] : cp1[2 * e - 4];
        float se1 = (e < 2) ? cp0[2 * e + 1] : cp1[2 * e - 3];
        vp[e] = f2b1(b2f1(vp[e]) * se0) | (f2b1(b2f1(vp[e] >> 16) * se1) << 16);
    }
    *(uint4*)&((unsigned short*)dst)[base] = v;
}

// ================= squared norms from hi/lo (partial over 128-c chunks) =================
__global__ void sqt_part_kernel(const short* __restrict__ H, const short* __restrict__ L,
                                int C, float* __restrict__ dst) {
    int m = blockIdx.x * 256 + threadIdx.x;
    int cb = blockIdx.y * 128;
    int ce = min(cb + 128, C);
    const unsigned short* Hp = (const unsigned short*)H;
    const unsigned short* Lp = (const unsigned short*)L;
    float s = 0.f;
    for (int c = cb; c < ce; c++) {
        float v = b2f1(Hp[(size_t)c * LDT + m]) + b2f1(Lp[(size_t)c * LDT + m]);
        s += v * v;
    }
    dst[(size_t)blockIdx.y * LDT + m] = s;
}
__global__ void sqt_red_kernel(const float* __restrict__ part, int NC, float* __restrict__ sq) {
    int m = blockIdx.x * 256 + threadIdx.x;
    float s = 0.f;
    for (int y = 0; y < NC; y++) s += part[(size_t)y * LDT + m];
    sq[m] = s;
}

// ====== adjacency + fused row-sum partials: W[b][j][i] = exp(2G - sq_i - sq_j) ======
// Output row-space = j (first MFMA operand = x_j frags), col (lane) = i.
// Off-diag partial sums per (i-block, j) -> Wpart; diag value -> diagW.
__global__ __launch_bounds__(256)
void adj_mfma_kernel(const short* __restrict__ XTh, const short* __restrict__ XTl,
                     int ck64, int Cvalid, const float* __restrict__ sq,
                     short* __restrict__ Wb, float* __restrict__ Wpart,
                     float* __restrict__ diagW) {
    __shared__ short Ah[128 * 64], Al[128 * 64], Bh[128 * 64], Bl[128 * 64];
    __shared__ float jpart[128][2];
    int tid = threadIdx.x, lane = tid & 63, w = tid >> 6;
    int wj = w >> 1, wi = w & 1;
    int b = blockIdx.z, i0 = blockIdx.x * 128, j0 = blockIdx.y * 128;
    size_t bo = (size_t)b * NN;
    f32x4 acc[4][4] = {};
    const unsigned short* Hs = (const unsigned short*)XTh;
    const unsigned short* Ls = (const unsigned short*)XTl;
    for (int t = 0; t < ck64; t++) {
        int c0 = t * 64;
        stage_tr(Ah, Hs, bo + i0, c0, Cvalid, tid);   // x_i hi
        stage_tr(Al, Ls, bo + i0, c0, Cvalid, tid);   // x_i lo
        stage_tr(Bh, Hs, bo + j0, c0, Cvalid, tid);   // x_j hi
        stage_tr(Bl, Ls, bo + j0, c0, Cvalid, tid);   // x_j lo
        __syncthreads();
        int la = lane & 15;
        #pragma unroll
        for (int ks = 0; ks < 2; ks++) {
            int kb = ks * 32 + (lane >> 4) * 8;
            bf16x8 jh[4], jl[4], ih[4], il[4];
            #pragma unroll
            for (int f = 0; f < 4; f++) {
                int jr = wj * 64 + f * 16 + la;
                jh[f] = *(const bf16x8*)&Bh[SW(jr, kb)];
                jl[f] = *(const bf16x8*)&Bl[SW(jr, kb)];
                int ir = wi * 64 + f * 16 + la;
                ih[f] = *(const bf16x8*)&Ah[SW(ir, kb)];
                il[f] = *(const bf16x8*)&Al[SW(ir, kb)];
            }
            #pragma unroll
            for (int fq = 0; fq < 4; fq++)
                #pragma unroll
                for (int fi = 0; fi < 4; fi++) {
                    acc[fq][fi] = __builtin_amdgcn_mfma_f32_16x16x32_bf16(jh[fq], ih[fi], acc[fq][fi], 0, 0, 0);
                    acc[fq][fi] = __builtin_amdgcn_mfma_f32_16x16x32_bf16(jh[fq], il[fi], acc[fq][fi], 0, 0, 0);
                    acc[fq][fi] = __builtin_amdgcn_mfma_f32_16x16x32_bf16(jl[fq], ih[fi], acc[fq][fi], 0, 0, 0);
                }
        }
        __syncthreads();
    }
    const float* sqb = sq + bo;
    unsigned short* Wout = (unsigned short*)Wb + bo * NN;
    float si_[4];
    int iloc[4];
    #pragma unroll
    for (int fi = 0; fi < 4; fi++) {
        iloc[fi] = i0 + wi * 64 + fi * 16 + (lane & 15);
        si_[fi] = sqb[iloc[fi]];
    }
    #pragma unroll
    for (int fq = 0; fq < 4; fq++) {
        int jb = j0 + wj * 64 + fq * 16 + (lane >> 4) * 4;
        #pragma unroll
        for (int r = 0; r < 4; r++) {
            int j = jb + r;
            float sj = sqb[j];
            float p = 0.f;
            #pragma unroll
            for (int fi = 0; fi < 4; fi++) {
                float val = __expf(2.f * ((const float*)&acc[fq][fi])[r] - si_[fi] - sj);
                Wout[(size_t)j * NN + iloc[fi]] = (unsigned short)f2b1(val);
                if (iloc[fi] == j) diagW[bo + j] = val;
                else p += val;
            }
            p += __shfl_xor(p, 1); p += __shfl_xor(p, 2);
            p += __shfl_xor(p, 4); p += __shfl_xor(p, 8);
            if ((lane & 15) == 0)
                jpart[wj * 64 + fq * 16 + (lane >> 4) * 4 + r][wi] = p;
        }
    }
    __syncthreads();
    if (tid < 128)
        Wpart[(size_t)blockIdx.x * (BB * NN) + bo + j0 + tid] = jpart[tid][0] + jpart[tid][1];
}

// ====== reduce partials -> coefficient vectors ======
__global__ void reduce_prep_kernel(const float* __restrict__ Wpart, const float* __restrict__ diagW,
                                   float* dinv, float* dinvP, float* cA1, float* cA2, float* cAV) {
    int idx = blockIdx.x * 256 + threadIdx.x;    // [0, 16384)
    float s = 0.f;
    #pragma unroll
    for (int x = 0; x < 8; x++) s += Wpart[(size_t)x * (BB * NN) + idx];
    float d = diagW[idx];
    float dv = rsqrtf(s + d);    // full sum (incl diag)
    float dp = rsqrtf(s);        // exact off-diag sum (no cancellation)
    dinv[idx] = dv; dinvP[idx] = dp;
    cA1[idx] = -dv; cA2[idx] = -2.f * dv; cAV[idx] = -dp;
}

// ====== W-GEMM (8 waves): Dst[c][i] = cA_i * sum_j W[i][j]*Bsc[c][j] (+ prevSign*Prev[c][i]) ======
// B operand is pre-scaled (dinv folded). Output row-space = c, col (lane) = i -> coalesced stores.
template<bool HAS_PREV, bool SKIP_DIAG, bool WRITE_SC>
__global__ __launch_bounds__(512)
void wgemm2_kernel(const short* __restrict__ W, const short* __restrict__ Bsc,
                   const float* __restrict__ cAvec, float prevSign,
                   const short* __restrict__ PrevT, const float* __restrict__ scVec,
                   short* __restrict__ DstT, short* __restrict__ DstSc, int Cvalid) {
    __shared__ short As[128 * 64], Bs[128 * 64];
    int tid = threadIdx.x, lane = tid & 63, w = tid >> 6;
    int wcc = w >> 2, wii = w & 3;               // wave tile: 64 c x 32 i
    int b = blockIdx.z, i0 = blockIdx.x * 128, c0 = blockIdx.y * 128;
    size_t bo = (size_t)b * NN;
    const unsigned short* Wp = (const unsigned short*)W + bo * NN;
    const unsigned short* Bp = (const unsigned short*)Bsc;
    f32x4 acc[4][2] = {};
    for (int k0 = 0; k0 < NN; k0 += 64) {
        #pragma unroll
        for (int n = 0; n < 2; n++) {
            int q = n * 512 + tid;
            int r = q >> 3, k8 = (q & 7) * 8;
            uint4 va = *(const uint4*)&Wp[(size_t)(i0 + r) * NN + k0 + k8];
            if (SKIP_DIAG) {
                int d = (i0 + r) - (k0 + k8);
                if ((unsigned)d < 8u) {
                    unsigned* vp = (unsigned*)&va;
                    vp[d >> 1] &= (d & 1) ? 0x0000ffffu : 0xffff0000u;
                }
            }
            *(uint4*)&As[SW(r, k8)] = va;
            uint4 vb = make_uint4(0, 0, 0, 0);
            if (c0 + r < Cvalid) vb = *(const uint4*)&Bp[(size_t)(c0 + r) * LDT + bo + k0 + k8];
            *(uint4*)&Bs[SW(r, k8)] = vb;
        }
        __syncthreads();
        int la = lane & 15;
        #pragma unroll
        for (int ks = 0; ks < 2; ks++) {
            int kb = ks * 32 + (lane >> 4) * 8;
            bf16x8 ac[4], bi[2];
            #pragma unroll
            for (int f = 0; f < 4; f++) ac[f] = *(const bf16x8*)&Bs[SW(wcc * 64 + f * 16 + la, kb)];
            #pragma unroll
            for (int f = 0; f < 2; f++) bi[f] = *(const bf16x8*)&As[SW(wii * 32 + f * 16 + la, kb)];
            #pragma unroll
            for (int fq = 0; fq < 4; fq++)
                #pragma unroll
                for (int fi = 0; fi < 2; fi++)
                    acc[fq][fi] = __builtin_amdgcn_mfma_f32_16x16x32_bf16(ac[fq], bi[fi], acc[fq][fi], 0, 0, 0);
        }
        __syncthreads();
    }
    const unsigned short* Pp = (const unsigned short*)PrevT;
    unsigned short* Dp = (unsigned short*)DstT;
    unsigned short* Sp = (unsigned short*)DstSc;
    #pragma unroll
    for (int fi = 0; fi < 2; fi++) {
        int i = i0 + wii * 32 + fi * 16 + (lane & 15);
        float ca = cAvec[bo + i];
        float sc = WRITE_SC ? scVec[bo + i] : 0.f;
        #pragma unroll
        for (int fq = 0; fq < 4; fq++) {
            int cb = c0 + wcc * 64 + fq * 16 + (lane >> 4) * 4;
            const float* av = (const float*)&acc[fq][fi];
            #pragma unroll
            for (int r = 0; r < 4; r++) {
                int c = cb + r;
                if (c < Cvalid) {
                    float v = ca * av[r];
                    if (HAS_PREV) v += prevSign * b2f1(Pp[(size_t)c * LDT + bo + i]);
                    Dp[(size_t)c * LDT + bo + i] = (unsigned short)f2b1(v);
                    if (WRITE_SC) Sp[(size_t)c * LDT + bo + i] = (unsigned short)f2b1(v * sc);
                }
            }
        }
    }
}

// ====== feature GEMM (8 waves): Out[co][m] = relu(sum_kk Zcat[m][kk]*Wt[kk][co] + bias) ======
__global__ __launch_bounds__(512)
void fgemm_mfma_kernel(const short* __restrict__ A0T, const short* __restrict__ ZrT,
                       const short* __restrict__ WtT, int Kp64, int KpValid, int Cpad,
                       const float* __restrict__ bias,
                       short* __restrict__ OutH, short* __restrict__ OutL) {
    __shared__ short As[128 * 64], Bs[128 * 64];
    int tid = threadIdx.x, lane = tid & 63, w = tid >> 6;
    int wco = w >> 2, wm = w & 3;                // wave tile: 64 co x 32 m
    int m0 = blockIdx.x * 128, co0 = blockIdx.y * 128;
    const unsigned short* A0 = (const unsigned short*)A0T;
    const unsigned short* Zr = (const unsigned short*)ZrT;
    const unsigned short* Wt = (const unsigned short*)WtT;
    f32x4 acc[4][2] = {};
    for (int kk0 = 0; kk0 < Kp64; kk0 += 64) {
        {   // A: transpose-stage Zcat rows kk (dual source), cols m0..m0+127
            int p = tid >> 4, h = tid & 15;
            int kg0 = kk0 + 2 * p;
            uint4 r0 = make_uint4(0, 0, 0, 0), r1 = make_uint4(0, 0, 0, 0);
            if (kg0 < KpValid) {
                const unsigned short* s0 = (kg0 < Cpad) ? (A0 + (size_t)kg0 * LDT)
                                                        : (Zr + (size_t)(kg0 - Cpad) * LDT);
                r0 = *(const uint4*)&s0[m0 + 8 * h];
            }
            if (kg0 + 1 < KpValid) {
                int kg1 = kg0 + 1;
                const unsigned short* s1 = (kg1 < Cpad) ? (A0 + (size_t)kg1 * LDT)
                                                        : (Zr + (size_t)(kg1 - Cpad) * LDT);
                r1 = *(const uint4*)&s1[m0 + 8 * h];
            }
            const unsigned* a0 = (const unsigned*)&r0;
            const unsigned* a1 = (const unsigned*)&r1;
            #pragma unroll
            for (int e = 0; e < 8; e++) {
                unsigned lo = (e & 1) ? (a0[e >> 1] >> 16) : (a0[e >> 1] & 0xffffu);
                unsigned hi = (e & 1) ? (a1[e >> 1] >> 16) : (a1[e >> 1] & 0xffffu);
                *(unsigned*)&As[SW(8 * h + e, 2 * p)] = lo | (hi << 16);
            }
        }
        #pragma unroll
        for (int n = 0; n < 2; n++) {           // B: weight rows co, pure copy
            int q = n * 512 + tid;
            int r = q >> 3, k8 = (q & 7) * 8;
            uint4 v = *(const uint4*)&Wt[(size_t)(co0 + r) * Kp64 + kk0 + k8];
            *(uint4*)&Bs[SW(r, k8)] = v;
        }
        __syncthreads();
        int la = lane & 15;
        #pragma unroll
        for (int ks = 0; ks < 2; ks++) {
            int kb = ks * 32 + (lane >> 4) * 8;
            bf16x8 ac[4], bm[2];
            #pragma unroll
            for (int f = 0; f < 4; f++) ac[f] = *(const bf16x8*)&Bs[SW(wco * 64 + f * 16 + la, kb)];
            #pragma unroll
            for (int f = 0; f < 2; f++) bm[f] = *(const bf16x8*)&As[SW(wm * 32 + f * 16 + la, kb)];
            #pragma unroll
            for (int fq = 0; fq < 4; fq++)
                #pragma unroll
                for (int fi = 0; fi < 2; fi++)
                    acc[fq][fi] = __builtin_amdgcn_mfma_f32_16x16x32_bf16(ac[fq], bm[fi], acc[fq][fi], 0, 0, 0);
        }
        __syncthreads();
    }
    unsigned short* OH = (unsigned short*)OutH;
    unsigned short* OL = (unsigned short*)OutL;
    #pragma unroll
    for (int fi = 0; fi < 2; fi++) {
        int m = m0 + wm * 32 + fi * 16 + (lane & 15);
        #pragma unroll
        for (int fq = 0; fq < 4; fq++) {
            int cb = co0 + wco * 64 + fq * 16 + (lane >> 4) * 4;
            const float* av = (const float*)&acc[fq][fi];
            #pragma unroll
            for (int r = 0; r < 4; r++) {
                int co = cb + r;
                float v = av[r] + bias[co];
                v = v > 0.f ? v : 0.f;
                unsigned ph = f2b1(v);
                unsigned pl = f2b1(v - b2f1(ph));
                OH[(size_t)co * LDT + m] = (unsigned short)ph;
                OL[(size_t)co * LDT + m] = (unsigned short)pl;
            }
        }
    }
}

// ====== M partials: Mpart[z][cj][ci] = sum_{m in chunk} XT[ci][m]*VT[cj][m] ======
__global__ __launch_bounds__(256)
void mgemm_mfma_kernel(const short* __restrict__ XT, const short* __restrict__ VT,
                       float* __restrict__ Mpart, int Cout, int kChunk) {
    __shared__ short As[128 * 64], Bs[128 * 64];
    int tid = threadIdx.x, lane = tid & 63, w = tid >> 6;
    int wcj = w >> 1, wci = w & 1;
    int ci0 = blockIdx.x * 128, cj0 = blockIdx.y * 128;
    int kStart = blockIdx.z * kChunk;
    const unsigned short* Xp = (const unsigned short*)XT + (size_t)ci0 * LDT;
    const unsigned short* Vp = (const unsigned short*)VT + (size_t)cj0 * LDT;
    f32x4 acc[4][4] = {};
    for (int k0 = kStart; k0 < kStart + kChunk; k0 += 64) {
        #pragma unroll
        for (int n = 0; n < 4; n++) {
            int q = n * 256 + tid;
            int r = q >> 3, k8 = (q & 7) * 8;
            *(uint4*)&As[SW(r, k8)] = *(const uint4*)&Xp[(size_t)r * LDT + k0 + k8];
            *(uint4*)&Bs[SW(r, k8)] = *(const uint4*)&Vp[(size_t)r * LDT + k0 + k8];
        }
        __syncthreads();
        int la = lane & 15;
        #pragma unroll
        for (int ks = 0; ks < 2; ks++) {
            int kb = ks * 32 + (lane >> 4) * 8;
            bf16x8 aj[4], bi[4];
            #pragma unroll
            for (int f = 0; f < 4; f++) {
                aj[f] = *(const bf16x8*)&Bs[SW(wcj * 64 + f * 16 + la, kb)];   // cj frags
                bi[f] = *(const bf16x8*)&As[SW(wci * 64 + f * 16 + la, kb)];   // ci frags
            }
            #pragma unroll
            for (int fq = 0; fq < 4; fq++)
                #pragma unroll
                for (int fi = 0; fi < 4; fi++)
                    acc[fq][fi] = __builtin_amdgcn_mfma_f32_16x16x32_bf16(aj[fq], bi[fi], acc[fq][fi], 0, 0, 0);
        }
        __syncthreads();
    }
    float* pt = Mpart + (size_t)blockIdx.z * Cout * Cout;
    #pragma unroll
    for (int fq = 0; fq < 4; fq++) {
        int cjb = cj0 + wcj * 64 + fq * 16 + (lane >> 4) * 4;
        #pragma unroll
        for (int fi = 0; fi < 4; fi++) {
            int ci = ci0 + wci * 64 + fi * 16 + (lane & 15);
            const float* av = (const float*)&acc[fq][fi];
            #pragma unroll
            for (int r = 0; r < 4; r++)
                pt[(size_t)(cjb + r) * Cout + ci] = av[r];
        }
    }
}

// ================= Frobenius norm of summed split-K partials (deterministic) =================
__global__ void fro1_kernel(const float* __restrict__ part, int nElem, int splitk,
                            float* __restrict__ blockSS) {
    int tid = threadIdx.x;
    float ss = 0.f;
    for (int idx = blockIdx.x * 256 + tid; idx < nElem; idx += 1024 * 256) {
        float s = 0.f;
        for (int z = 0; z < splitk; z++) s += part[(size_t)z * nElem + idx];
        ss += s * s;
    }
    __shared__ float red[256];
    red[tid] = ss; __syncthreads();
    for (int m = 128; m >= 1; m >>= 1) { if (tid < m) red[tid] += red[tid + m]; __syncthreads(); }
    if (tid == 0) blockSS[blockIdx.x] = red[0];
}
__global__ void fro2_kernel(const float* __restrict__ blockSS, float* __restrict__ outp) {
    int tid = threadIdx.x;
    float s = 0.f;
    for (int i = tid; i < 1024; i += 256) s += blockSS[i];
    __shared__ float red[256];
    red[tid] = s; __syncthreads();
    for (int m = 128; m >= 1; m >>= 1) { if (tid < m) red[tid] += red[tid + m]; __syncthreads(); }
    if (tid == 0) *outp = sqrtf(red[0]);
}

// ================= max-pool over points: one wave per (b,co) row, coalesced =================
__global__ void pool_kernel(const short* __restrict__ H, const short* __restrict__ L,
                            float* __restrict__ out) {
    int wave = threadIdx.x >> 6, lane = threadIdx.x & 63;
    int r = blockIdx.x * 4 + wave;             // [0, 16384): r = co*16 + b
    int co = r >> 4, b = r & 15;
    const unsigned short* h = (const unsigned short*)H + (size_t)co * LDT + b * NN;
    const unsigned short* l = (const unsigned short*)L + (size_t)co * LDT + b * NN;
    float m = -1e30f;
    #pragma unroll
    for (int it = 0; it < 2; it++) {
        int n8 = (it * 64 + lane) * 8;
        uint4 vh = *(const uint4*)&h[n8];
        uint4 vl = *(const uint4*)&l[n8];
        const unsigned* hp = (const unsigned*)&vh;
        const unsigned* lp = (const unsigned*)&vl;
        #pragma unroll
        for (int e = 0; e < 4; e++) {
            m = fmaxf(m, b2f1(hp[e]) + b2f1(lp[e]));
            m = fmaxf(m, b2f1(hp[e] >> 16) + b2f1(lp[e] >> 16));
        }
    }
    m = wave_max(m);
    if (lane == 0) out[b * 1024 + co] = m;
}

// ================= small FC: one wave per (b,o) output, lanes stride K (coalesced) =================
__global__ void fc_kernel(const float* __restrict__ in, const float* __restrict__ WtT,
                          const float* __restrict__ bias, float* __restrict__ out,
                          int K, int O, int doRelu) {
    int wave = threadIdx.x >> 6, lane = threadIdx.x & 63;
    int idx = blockIdx.x * 4 + wave;           // [0, 16*O)
    if (idx >= 16 * O) return;
    int b = idx / O, o = idx - b * O;
    const float* ib = in + (size_t)b * K;
    const float* wr = WtT + (size_t)o * K;
    float s = 0.f;
    for (int k = lane * 4; k < K; k += 256) {
        f4 a = *(const f4*)&ib[k];
        f4 wv = *(const f4*)&wr[k];
        s += a.x * wv.x + a.y * wv.y + a.z * wv.z + a.w * wv.w;
    }
    s = wave_sum(s);
    if (lane == 0) {
        s += bias[o];
        if (doRelu) s = fmaxf(s, 0.f);
        out[(size_t)b * O + o] = s;
    }
}

extern "C" void kernel_launch(void* const* d_in, const int* in_sizes, int n_in,
                              void* d_out, int out_size, void* d_ws, size_t ws_size,
                              hipStream_t stream) {
    const float* x   = (const float*)d_in[0];
    const float* w1  = (const float*)d_in[4];
    const float* b1  = (const float*)d_in[5];
    const float* w2  = (const float*)d_in[6];
    const float* b2  = (const float*)d_in[7];
    const float* w3  = (const float*)d_in[8];
    const float* b3  = (const float*)d_in[9];
    const float* fw1 = (const float*)d_in[10];
    const float* fb1 = (const float*)d_in[11];
    const float* fw2 = (const float*)d_in[12];
    const float* fb2 = (const float*)d_in[13];
    const float* fw3 = (const float*)d_in[14];
    const float* fb3 = (const float*)d_in[15];
    float* out = (float*)d_out;

    char* ws = (char*)d_ws;
    size_t off = 0;
    auto alloc = [&](size_t bytes) -> void* {
        void* p = ws + off; off += (bytes + 255) & ~(size_t)255; return p;
    };
    short* Wbuf = (short*)alloc((size_t)BB * NN * NN * 2);   // 32 MiB; Mpart aliases after V-step
    short* Zbuf = (short*)alloc((size_t)1024 * LDT * 2);     // 32 MiB raw Z slices; V output later
    short* ZSc  = (short*)alloc((size_t)1024 * LDT * 2);     // 32 MiB scaled Z slices / scaled Out (V)
    short* Z0Sc = (short*)alloc((size_t)512 * LDT * 2);      // 16 MiB scaled Z0 (first wgemm B)
    short* o1H  = (short*)alloc((size_t)128 * LDT * 2);
    short* o1L  = (short*)alloc((size_t)128 * LDT * 2);
    short* o2H  = (short*)alloc((size_t)512 * LDT * 2);
    short* o2L  = (short*)alloc((size_t)512 * LDT * 2);
    short* o3H  = (short*)alloc((size_t)1024 * LDT * 2);
    short* o3L  = (short*)alloc((size_t)1024 * LDT * 2);
    short* xTh  = (short*)alloc((size_t)8 * LDT * 2);
    short* xTl  = (short*)alloc((size_t)8 * LDT * 2);
    short* WtT  = (short*)alloc((size_t)1024 * 1536 * 2);
    float* fwT1 = (float*)alloc((size_t)512 * 1024 * 4);
    float* fwT2 = (float*)alloc((size_t)128 * 512 * 4);
    float* fwT3 = (float*)alloc((size_t)10 * 128 * 4);
    float* sqpart = (float*)alloc((size_t)8 * LDT * 4);
    float* Wpart  = (float*)alloc((size_t)8 * BB * NN * 4);
    float* diagW  = (float*)alloc(BB * NN * 4);
    float* sq    = (float*)alloc(BB * NN * 4);
    float* dinv  = (float*)alloc(BB * NN * 4);
    float* dinvP = (float*)alloc(BB * NN * 4);
    float* cA1   = (float*)alloc(BB * NN * 4);
    float* cA2   = (float*)alloc(BB * NN * 4);
    float* cAV   = (float*)alloc(BB * NN * 4);
    float* pooled= (float*)alloc(BB * 1024 * 4);
    float* h1    = (float*)alloc(BB * 512 * 4);
    float* h2    = (float*)alloc(BB * 128 * 4);
    float* blockSS = (float*)alloc(1024 * 4);
    float* Mpart = (float*)Wbuf;      // alias: W dead after V-step
    (void)ws_size; (void)in_sizes; (void)n_in; (void)out_size;

    struct Layer {
        const short *XTh, *XTl;       // input features (transposed hi/lo)
        int C, ck64, K, Cpad, shift, Kp64, KpValid, Cout, splitk, rIdx;
        const float *Wk, *bk;
        short *OutH, *OutL;
    };
    Layer L[3] = {
        { xTh, xTl, 8,   1, 6, 8,   3, 64,   48,   128,  64, 160, w1, b1, o1H, o1L },
        { o1H, o1L, 128, 2, 5, 128, 7, 640,  640,  512,  32, 161, w2, b2, o2H, o2L },
        { o2H, o2L, 512, 8, 3, 512, 9, 1536, 1536, 1024, 8,  162, w3, b3, o3H, o3L },
    };

    xt_prep_kernel<<<LDT / 256, 256, 0, stream>>>(x, xTh, xTl);
    wtrans_kernel<<<(1024 * 512 + 255) / 256, 256, 0, stream>>>(fw1, fwT1, 1024, 512);
    wtrans_kernel<<<(512 * 128 + 255) / 256, 256, 0, stream>>>(fw2, fwT2, 512, 128);
    wtrans_kernel<<<(128 * 10 + 255) / 256, 256, 0, stream>>>(fw3, fwT3, 128, 10);

    for (int l = 0; l < 3; l++) {
        const Layer& P = L[l];
        int NC = (P.C + 127) / 128;
        wtt_prep_kernel<<<(P.Cout * P.Kp64 + 255) / 256, 256, 0, stream>>>(
            P.Wk, WtT, P.Kp64, P.KpValid, P.Cpad - 1, P.shift, (l == 0) ? 6 : P.C, P.Cout);
        sqt_part_kernel<<<dim3(LDT / 256, NC), 256, 0, stream>>>(P.XTh, P.XTl, P.C, sqpart);
        sqt_red_kernel<<<LDT / 256, 256, 0, stream>>>(sqpart, NC, sq);
        adj_mfma_kernel<<<dim3(8, 8, BB), 256, 0, stream>>>(P.XTh, P.XTl, P.ck64, P.C, sq,
                                                            Wbuf, Wpart, diagW);
        reduce_prep_kernel<<<BB * NN / 256, 256, 0, stream>>>(Wpart, diagW, dinv, dinvP, cA1, cA2, cAV);

        // scaled Z0 for the first wgemm's B operand
        scale_sc_kernel<<<(P.Cpad * LDT / 8 + 255) / 256, 256, 0, stream>>>(
            P.XTh, dinv, Z0Sc, P.Cpad * LDT / 8);

        int cT = (P.Cpad + 127) / 128;
        auto sliceR = [&](int k) -> short* { return Zbuf + (size_t)(k - 1) * P.Cpad * LDT; };
        auto sliceS = [&](int k) -> short* { return ZSc  + (size_t)(k - 1) * P.Cpad * LDT; };
        // Z1 = -dinv .* (W @ Z0sc)
        if (P.K > 2)
            wgemm2_kernel<false, false, true><<<dim3(8, cT, BB), 512, 0, stream>>>(
                Wbuf, Z0Sc, cA1, 0.f, (const short*)nullptr, dinv, sliceR(1), sliceS(1), P.Cpad);
        else
            wgemm2_kernel<false, false, false><<<dim3(8, cT, BB), 512, 0, stream>>>(
                Wbuf, Z0Sc, cA1, 0.f, (const short*)nullptr, dinv, sliceR(1), (short*)nullptr, P.Cpad);
        // Zk = -2*dinv .* (W @ Zsc_{k-1}) - Z_{k-2}
        for (int k = 2; k < P.K; k++) {
            const short* prevT = (k == 2) ? P.XTh : sliceR(k - 2);
            if (k < P.K - 1)
                wgemm2_kernel<true, false, true><<<dim3(8, cT, BB), 512, 0, stream>>>(
                    Wbuf, sliceS(k - 1), cA2, -1.f, prevT, dinv, sliceR(k), sliceS(k), P.Cpad);
            else
                wgemm2_kernel<true, false, false><<<dim3(8, cT, BB), 512, 0, stream>>>(
                    Wbuf, sliceS(k - 1), cA2, -1.f, prevT, dinv, sliceR(k), (short*)nullptr, P.Cpad);
        }
        fgemm_mfma_kernel<<<dim3(LDT / 128, P.Cout / 128), 512, 0, stream>>>(
            P.XTh, Zbuf, WtT, P.Kp64, P.KpValid, P.Cpad, P.bk, P.OutH, P.OutL);
        // V = out - dinvP .* (W_nodiag @ (dinvP .* out)); scaled out -> ZSc, V -> Zbuf
        scale_sc_kernel<<<(P.Cout * LDT / 8 + 255) / 256, 256, 0, stream>>>(
            P.OutH, dinvP, ZSc, P.Cout * LDT / 8);
        wgemm2_kernel<true, true, false><<<dim3(8, P.Cout / 128, BB), 512, 0, stream>>>(
            Wbuf, ZSc, cAV, 1.f, P.OutH, dinvP, Zbuf, (short*)nullptr, P.Cout);
        int kChunk = LDT / P.splitk;
        mgemm_mfma_kernel<<<dim3(P.Cout / 128, P.Cout / 128, P.splitk), 256, 0, stream>>>(
            P.OutH, Zbuf, Mpart, P.Cout, kChunk);
        fro1_kernel<<<1024, 256, 0, stream>>>(Mpart, P.Cout * P.Cout, P.splitk, blockSS);
        fro2_kernel<<<1, 256, 0, stream>>>(blockSS, out + P.rIdx);
    }
    pool_kernel<<<16384 / 4, 256, 0, stream>>>(o3H, o3L, pooled);
    fc_kernel<<<(16 * 512 + 3) / 4, 256, 0, stream>>>(pooled, fwT1, fb1, h1, 1024, 512, 1);
    fc_kernel<<<(16 * 128 + 3) / 4, 256, 0, stream>>>(h1, fwT2, fb2, h2, 512, 128, 1);
    fc_kernel<<<(16 * 10 + 3) / 4, 256, 0, stream>>>(h2, fwT3, fb3, out, 128, 10, 0);
}